// Round 1
// baseline (459.028 us; speedup 1.0000x reference)
//
#include <hip/hip_runtime.h>
#include <hip/hip_bf16.h>

#define N_NODES 100000
#define N_EDGES 1600000
#define N_GRAPHS 64

// ---------------- CSR build ----------------

__global__ __launch_bounds__(256) void deg_kernel(const int* __restrict__ dst,
                                                  int* __restrict__ deg, int E) {
    int e = blockIdx.x * 256 + threadIdx.x;
    if (e < E) atomicAdd(&deg[dst[e]], 1);
}

// Block b sums deg[b*1024 .. b*1024+1023] -> partials[b]
__global__ __launch_bounds__(256) void scan_partial(const int* __restrict__ deg,
                                                    int* __restrict__ partials, int n) {
    __shared__ int s[256];
    int b = blockIdx.x, t = threadIdx.x;
    int base = b * 1024;
    int sum = 0;
#pragma unroll
    for (int i = 0; i < 4; ++i) {
        int idx = base + i * 256 + t;
        if (idx < n) sum += deg[idx];
    }
    s[t] = sum;
    __syncthreads();
    for (int o = 128; o > 0; o >>= 1) {
        if (t < o) s[t] += s[t + o];
        __syncthreads();
    }
    if (t == 0) partials[b] = s[0];
}

__global__ void scan_total(int* partials, int nb) {
    if (threadIdx.x == 0 && blockIdx.x == 0) {
        int run = 0;
        for (int i = 0; i < nb; ++i) {
            int v = partials[i];
            partials[i] = run;
            run += v;
        }
    }
}

// Block b: exclusive scan of its 1024 deg values + partials[b] -> rp, cur
__global__ __launch_bounds__(256) void scan_write(const int* __restrict__ deg,
                                                  const int* __restrict__ partials,
                                                  int* __restrict__ rp, int* __restrict__ cur,
                                                  int n, int E) {
    __shared__ int s[256];
    int b = blockIdx.x, t = threadIdx.x;
    int base = b * 1024 + t * 4;
    int d[4];
    int sum = 0;
#pragma unroll
    for (int i = 0; i < 4; ++i) {
        int idx = base + i;
        d[i] = (idx < n) ? deg[idx] : 0;
        sum += d[i];
    }
    s[t] = sum;
    __syncthreads();
    // Hillis-Steele inclusive scan over the 256 per-thread sums
    for (int o = 1; o < 256; o <<= 1) {
        int tmp = 0;
        if (t >= o) tmp = s[t - o];
        __syncthreads();
        s[t] += tmp;
        __syncthreads();
    }
    int running = partials[b] + (s[t] - sum);  // exclusive prefix for this thread
#pragma unroll
    for (int i = 0; i < 4; ++i) {
        int idx = base + i;
        if (idx < n) {
            rp[idx] = running;
            cur[idx] = running;
            running += d[i];
        }
    }
    if (b == 0 && t == 0) rp[n] = E;
}

__global__ __launch_bounds__(256) void csr_fill(const int* __restrict__ src,
                                                const int* __restrict__ dst,
                                                int* __restrict__ cur, int* __restrict__ col,
                                                int E) {
    int e = blockIdx.x * 256 + threadIdx.x;
    if (e < E) {
        int v = dst[e];
        int p = atomicAdd(&cur[v], 1);
        col[p] = src[e];
    }
}

// ---------------- Layer 1 (din=6, dout=16): one thread per node ----------------

__global__ __launch_bounds__(256) void sage_layer1(const float* __restrict__ feat,
                                                   const int* __restrict__ rp,
                                                   const int* __restrict__ col,
                                                   const float* __restrict__ W,
                                                   const float* __restrict__ bias,
                                                   float* __restrict__ hout, int n) {
    __shared__ float sW[6 * 16];
    __shared__ float sB[16];
    int tid = threadIdx.x;
    if (tid < 96) sW[tid] = W[tid];
    if (tid < 16) sB[tid] = bias[tid];
    __syncthreads();
    int v = blockIdx.x * 256 + tid;
    if (v >= n) return;
    int r0 = rp[v], r1 = rp[v + 1];
    float acc[6] = {0.f, 0.f, 0.f, 0.f, 0.f, 0.f};
    const float2* f2 = reinterpret_cast<const float2*>(feat);
    for (int j = r0; j < r1; ++j) {
        int u = col[j];
        float2 a = f2[u * 3 + 0], b = f2[u * 3 + 1], c = f2[u * 3 + 2];
        acc[0] += a.x; acc[1] += a.y;
        acc[2] += b.x; acc[3] += b.y;
        acc[4] += c.x; acc[5] += c.y;
    }
    {
        float2 a = f2[v * 3 + 0], b = f2[v * 3 + 1], c = f2[v * 3 + 2];
        acc[0] += a.x; acc[1] += a.y;
        acc[2] += b.x; acc[3] += b.y;
        acc[4] += c.x; acc[5] += c.y;
    }
    float inv = 1.0f / (float)(r1 - r0 + 1);
#pragma unroll
    for (int k = 0; k < 6; ++k) acc[k] *= inv;
    float outv[16];
#pragma unroll
    for (int o = 0; o < 16; ++o) outv[o] = sB[o];
#pragma unroll
    for (int k = 0; k < 6; ++k) {
#pragma unroll
        for (int o = 0; o < 16; ++o) outv[o] += acc[k] * sW[k * 16 + o];
    }
    float4* ho4 = reinterpret_cast<float4*>(hout + (size_t)v * 16);
#pragma unroll
    for (int q = 0; q < 4; ++q) {
        float4 r;
        r.x = fmaxf(outv[q * 4 + 0], 0.f);
        r.y = fmaxf(outv[q * 4 + 1], 0.f);
        r.z = fmaxf(outv[q * 4 + 2], 0.f);
        r.w = fmaxf(outv[q * 4 + 3], 0.f);
        ho4[q] = r;
    }
}

// ---------------- Generic fused layer (din in {16,32,64}) ----------------
// WPN = DIN/4 threads per node gather float4 slices; GEMM from LDS.

template <int DIN, int DOUT>
__global__ __launch_bounds__(256) void sage_layer(const float* __restrict__ hin,
                                                  const int* __restrict__ rp,
                                                  const int* __restrict__ col,
                                                  const float* __restrict__ W,
                                                  const float* __restrict__ bias,
                                                  float* __restrict__ hout, int n) {
    constexpr int WPN = DIN / 4;    // threads per node
    constexpr int NPB = 256 / WPN;  // nodes per block
    constexpr int OPT = DOUT / WPN; // outputs per thread in GEMM phase
    __shared__ float sW[DIN * DOUT];
    __shared__ float sB[DOUT];
    __shared__ float sH[NPB][DIN + 1];  // +1 pad: conflict-free phase-2 reads

    int tid = threadIdx.x;
    for (int i = tid; i < DIN * DOUT; i += 256) sW[i] = W[i];
    if (tid < DOUT) sB[tid] = bias[tid];

    int sub = tid / WPN;
    int t = tid % WPN;
    int v = blockIdx.x * NPB + sub;

    if (v < n) {
        int r0 = rp[v], r1 = rp[v + 1];
        const float4* hin4 = reinterpret_cast<const float4*>(hin);
        constexpr int S4 = DIN / 4;
        float4 acc = {0.f, 0.f, 0.f, 0.f};
        for (int j = r0; j < r1; ++j) {
            int u = col[j];
            float4 x = hin4[(size_t)u * S4 + t];
            acc.x += x.x; acc.y += x.y; acc.z += x.z; acc.w += x.w;
        }
        float4 sx = hin4[(size_t)v * S4 + t];
        float inv = 1.0f / (float)(r1 - r0 + 1);
        acc.x = (acc.x + sx.x) * inv;
        acc.y = (acc.y + sx.y) * inv;
        acc.z = (acc.z + sx.z) * inv;
        acc.w = (acc.w + sx.w) * inv;
        sH[sub][t * 4 + 0] = acc.x;
        sH[sub][t * 4 + 1] = acc.y;
        sH[sub][t * 4 + 2] = acc.z;
        sH[sub][t * 4 + 3] = acc.w;
    }
    __syncthreads();
    if (v < n) {
        int o0 = t * OPT;
        float accO[OPT];
#pragma unroll
        for (int i = 0; i < OPT; ++i) accO[i] = sB[o0 + i];
#pragma unroll 4
        for (int k = 0; k < DIN; ++k) {
            float hk = sH[sub][k];
#pragma unroll
            for (int i = 0; i < OPT; ++i) accO[i] += hk * sW[k * DOUT + o0 + i];
        }
#pragma unroll
        for (int i = 0; i < OPT; i += 4) {
            float4 r;
            r.x = fmaxf(accO[i + 0], 0.f);
            r.y = fmaxf(accO[i + 1], 0.f);
            r.z = fmaxf(accO[i + 2], 0.f);
            r.w = fmaxf(accO[i + 3], 0.f);
            *reinterpret_cast<float4*>(hout + (size_t)v * DOUT + o0 + i) = r;
        }
    }
}

// ---------------- Pooling: per-graph mean over sorted graph_ids ----------------

__device__ __forceinline__ int lower_bound_i(const int* __restrict__ a, int n, int key) {
    int lo = 0, hi = n;
    while (lo < hi) {
        int m = (lo + hi) >> 1;
        if (a[m] < key) lo = m + 1; else hi = m;
    }
    return lo;
}

__global__ __launch_bounds__(256) void pool_kernel(const float* __restrict__ h,
                                                   const int* __restrict__ gids,
                                                   float* __restrict__ out, int n) {
    int bx = blockIdx.x;
    int g = bx >> 3, s = bx & 7;
    int start = lower_bound_i(gids, n, g);
    int end = lower_bound_i(gids, n, g + 1);
    int len = end - start;
    float inv = 1.0f / (float)(len > 0 ? len : 1);
    int chunk = (len + 7) / 8;
    int s0 = start + s * chunk;
    int s1 = min(s0 + chunk, end);
    int t = threadIdx.x;
    int d = t & 63, j = t >> 6;
    float acc = 0.f;
    for (int i = s0 + j; i < s1; i += 4) acc += h[(size_t)i * 64 + d];
    __shared__ float red[4][64];
    red[j][d] = acc;
    __syncthreads();
    if (j == 0) {
        float tot = (red[0][d] + red[1][d]) + (red[2][d] + red[3][d]);
        atomicAdd(&out[g * 64 + d], tot * inv);
    }
}

// ---------------- launch ----------------

extern "C" void kernel_launch(void* const* d_in, const int* in_sizes, int n_in,
                              void* d_out, int out_size, void* d_ws, size_t ws_size,
                              hipStream_t stream) {
    const int N = N_NODES, E = N_EDGES;
    const float* feat = (const float*)d_in[0];
    const int* src = (const int*)d_in[1];
    const int* dst = (const int*)d_in[2];
    const int* gids = (const int*)d_in[3];
    const float* W1 = (const float*)d_in[4];
    const float* b1 = (const float*)d_in[5];
    const float* W2 = (const float*)d_in[6];
    const float* b2 = (const float*)d_in[7];
    const float* W3 = (const float*)d_in[8];
    const float* b3 = (const float*)d_in[9];
    const float* W4 = (const float*)d_in[10];
    const float* b4 = (const float*)d_in[11];
    float* out = (float*)d_out;

    // workspace layout
    int* deg = (int*)d_ws;            // N
    int* rp = deg + N;                // N+1
    int* cur = rp + N + 1;            // N
    int* partials = cur + N;          // 128
    int* col = partials + 128;        // E
    size_t off = (size_t)((char*)(col + E) - (char*)d_ws);
    off = (off + 15) & ~(size_t)15;
    float* h0 = (float*)((char*)d_ws + off);  // N*64
    float* h1 = h0 + (size_t)N * 64;          // N*64

    hipMemsetAsync(deg, 0, (size_t)N * sizeof(int), stream);
    hipMemsetAsync(out, 0, (size_t)N_GRAPHS * 64 * sizeof(float), stream);

    deg_kernel<<<(E + 255) / 256, 256, 0, stream>>>(dst, deg, E);
    const int NB = (N + 1023) / 1024;  // 98
    scan_partial<<<NB, 256, 0, stream>>>(deg, partials, N);
    scan_total<<<1, 64, 0, stream>>>(partials, NB);
    scan_write<<<NB, 256, 0, stream>>>(deg, partials, rp, cur, N, E);
    csr_fill<<<(E + 255) / 256, 256, 0, stream>>>(src, dst, cur, col, E);

    sage_layer1<<<(N + 255) / 256, 256, 0, stream>>>(feat, rp, col, W1, b1, h0, N);
    sage_layer<16, 32><<<(N + 63) / 64, 256, 0, stream>>>(h0, rp, col, W2, b2, h1, N);
    sage_layer<32, 64><<<(N + 31) / 32, 256, 0, stream>>>(h1, rp, col, W3, b3, h0, N);
    sage_layer<64, 64><<<(N + 15) / 16, 256, 0, stream>>>(h0, rp, col, W4, b4, h1, N);

    pool_kernel<<<N_GRAPHS * 8, 256, 0, stream>>>(h1, gids, out, N);
}

// Round 2
// 375.828 us; speedup vs baseline: 1.2214x; 1.2214x over previous
//
#include <hip/hip_runtime.h>
#include <hip/hip_bf16.h>

#define N_NODES 100000
#define N_EDGES 1600000
#define N_GRAPHS 64

// ---------------- CSR build ----------------

__global__ __launch_bounds__(256) void deg_kernel(const int* __restrict__ dst,
                                                  int* __restrict__ deg, int E) {
    int e = blockIdx.x * 256 + threadIdx.x;
    if (e < E) atomicAdd(&deg[dst[e]], 1);
}

// Block b sums deg[b*1024 .. b*1024+1023] -> partials[b]
__global__ __launch_bounds__(256) void scan_partial(const int* __restrict__ deg,
                                                    int* __restrict__ partials, int n) {
    __shared__ int s[256];
    int b = blockIdx.x, t = threadIdx.x;
    int base = b * 1024;
    int sum = 0;
#pragma unroll
    for (int i = 0; i < 4; ++i) {
        int idx = base + i * 256 + t;
        if (idx < n) sum += deg[idx];
    }
    s[t] = sum;
    __syncthreads();
    for (int o = 128; o > 0; o >>= 1) {
        if (t < o) s[t] += s[t + o];
        __syncthreads();
    }
    if (t == 0) partials[b] = s[0];
}

__global__ void scan_total(int* partials, int nb) {
    if (threadIdx.x == 0 && blockIdx.x == 0) {
        int run = 0;
        for (int i = 0; i < nb; ++i) {
            int v = partials[i];
            partials[i] = run;
            run += v;
        }
    }
}

// Block b: exclusive scan of its 1024 deg values + partials[b] -> rp, cur
__global__ __launch_bounds__(256) void scan_write(const int* __restrict__ deg,
                                                  const int* __restrict__ partials,
                                                  int* __restrict__ rp, int* __restrict__ cur,
                                                  int n, int E) {
    __shared__ int s[256];
    int b = blockIdx.x, t = threadIdx.x;
    int base = b * 1024 + t * 4;
    int d[4];
    int sum = 0;
#pragma unroll
    for (int i = 0; i < 4; ++i) {
        int idx = base + i;
        d[i] = (idx < n) ? deg[idx] : 0;
        sum += d[i];
    }
    s[t] = sum;
    __syncthreads();
    for (int o = 1; o < 256; o <<= 1) {
        int tmp = 0;
        if (t >= o) tmp = s[t - o];
        __syncthreads();
        s[t] += tmp;
        __syncthreads();
    }
    int running = partials[b] + (s[t] - sum);
#pragma unroll
    for (int i = 0; i < 4; ++i) {
        int idx = base + i;
        if (idx < n) {
            rp[idx] = running;
            cur[idx] = running;
            running += d[i];
        }
    }
    if (b == 0 && t == 0) rp[n] = E;
}

// XCD-partitioned fill: partition p (blockIdx&7 ~ XCD) only writes col slots for
// dst in its 1/8 node range -> each XCD's write window ~0.8MB stays L2-resident,
// lines end fully dirty (no partial-line writeback amplification).
__global__ __launch_bounds__(256) void csr_fill_part(const int* __restrict__ src,
                                                     const int* __restrict__ dst,
                                                     int* __restrict__ cur,
                                                     int* __restrict__ col, int E) {
    const int p = blockIdx.x & 7;
    const int c = blockIdx.x >> 3;
    const int nchunks = gridDim.x >> 3;
    const int lo = p * (N_NODES / 8);
    const int hi = (p == 7) ? N_NODES : lo + (N_NODES / 8);
    for (int e = c * 256 + threadIdx.x; e < E; e += nchunks * 256) {
        int v = dst[e];
        if (v >= lo && v < hi) {
            int pos = atomicAdd(&cur[v], 1);
            col[pos] = src[e];
        }
    }
}

// ---------------- Layer 1 (din=6, dout=16): one thread per node ----------------

__global__ __launch_bounds__(256) void sage_layer1(const float* __restrict__ feat,
                                                   const int* __restrict__ rp,
                                                   const int* __restrict__ col,
                                                   const float* __restrict__ W,
                                                   const float* __restrict__ bias,
                                                   float* __restrict__ hout, int n) {
    __shared__ float sW[6 * 16];
    __shared__ float sB[16];
    int tid = threadIdx.x;
    if (tid < 96) sW[tid] = W[tid];
    if (tid < 16) sB[tid] = bias[tid];
    __syncthreads();
    int v = blockIdx.x * 256 + tid;
    if (v >= n) return;
    int r0 = rp[v], r1 = rp[v + 1];
    float acc[6] = {0.f, 0.f, 0.f, 0.f, 0.f, 0.f};
    const float2* f2 = reinterpret_cast<const float2*>(feat);
    int j = r0;
    for (; j + 4 <= r1; j += 4) {
        int u0 = col[j], u1 = col[j + 1], u2 = col[j + 2], u3 = col[j + 3];
        float2 a0 = f2[u0 * 3 + 0], b0 = f2[u0 * 3 + 1], c0 = f2[u0 * 3 + 2];
        float2 a1 = f2[u1 * 3 + 0], b1 = f2[u1 * 3 + 1], c1 = f2[u1 * 3 + 2];
        float2 a2 = f2[u2 * 3 + 0], b2 = f2[u2 * 3 + 1], c2 = f2[u2 * 3 + 2];
        float2 a3 = f2[u3 * 3 + 0], b3 = f2[u3 * 3 + 1], c3 = f2[u3 * 3 + 2];
        acc[0] += (a0.x + a1.x) + (a2.x + a3.x);
        acc[1] += (a0.y + a1.y) + (a2.y + a3.y);
        acc[2] += (b0.x + b1.x) + (b2.x + b3.x);
        acc[3] += (b0.y + b1.y) + (b2.y + b3.y);
        acc[4] += (c0.x + c1.x) + (c2.x + c3.x);
        acc[5] += (c0.y + c1.y) + (c2.y + c3.y);
    }
    for (; j < r1; ++j) {
        int u = col[j];
        float2 a = f2[u * 3 + 0], b = f2[u * 3 + 1], c = f2[u * 3 + 2];
        acc[0] += a.x; acc[1] += a.y;
        acc[2] += b.x; acc[3] += b.y;
        acc[4] += c.x; acc[5] += c.y;
    }
    {
        float2 a = f2[v * 3 + 0], b = f2[v * 3 + 1], c = f2[v * 3 + 2];
        acc[0] += a.x; acc[1] += a.y;
        acc[2] += b.x; acc[3] += b.y;
        acc[4] += c.x; acc[5] += c.y;
    }
    float inv = 1.0f / (float)(r1 - r0 + 1);
#pragma unroll
    for (int k = 0; k < 6; ++k) acc[k] *= inv;
    float outv[16];
#pragma unroll
    for (int o = 0; o < 16; ++o) outv[o] = sB[o];
#pragma unroll
    for (int k = 0; k < 6; ++k) {
#pragma unroll
        for (int o = 0; o < 16; ++o) outv[o] += acc[k] * sW[k * 16 + o];
    }
    float4* ho4 = reinterpret_cast<float4*>(hout + (size_t)v * 16);
#pragma unroll
    for (int q = 0; q < 4; ++q) {
        float4 r;
        r.x = fmaxf(outv[q * 4 + 0], 0.f);
        r.y = fmaxf(outv[q * 4 + 1], 0.f);
        r.z = fmaxf(outv[q * 4 + 2], 0.f);
        r.w = fmaxf(outv[q * 4 + 3], 0.f);
        ho4[q] = r;
    }
}

// ---------------- Generic fused layer (din in {16,32,64}) ----------------
// WPN = DIN/4 threads per node gather float4 slices (4-edge unrolled for MLP);
// per-node GEMM from LDS.

template <int DIN, int DOUT>
__global__ __launch_bounds__(256) void sage_layer(const float* __restrict__ hin,
                                                  const int* __restrict__ rp,
                                                  const int* __restrict__ col,
                                                  const float* __restrict__ W,
                                                  const float* __restrict__ bias,
                                                  float* __restrict__ hout, int n) {
    constexpr int WPN = DIN / 4;
    constexpr int NPB = 256 / WPN;
    constexpr int OPT = DOUT / WPN;
    __shared__ float sW[DIN * DOUT];
    __shared__ float sB[DOUT];
    __shared__ float sH[NPB][DIN + 1];

    int tid = threadIdx.x;
    for (int i = tid; i < DIN * DOUT; i += 256) sW[i] = W[i];
    if (tid < DOUT) sB[tid] = bias[tid];

    int sub = tid / WPN;
    int t = tid % WPN;
    int v = blockIdx.x * NPB + sub;

    if (v < n) {
        int r0 = rp[v], r1 = rp[v + 1];
        const float4* hin4 = reinterpret_cast<const float4*>(hin);
        constexpr int S4 = DIN / 4;
        float4 a0 = {0.f, 0.f, 0.f, 0.f}, a1 = {0.f, 0.f, 0.f, 0.f};
        float4 a2 = {0.f, 0.f, 0.f, 0.f}, a3 = {0.f, 0.f, 0.f, 0.f};
        int j = r0;
        for (; j + 4 <= r1; j += 4) {
            int u0 = col[j], u1 = col[j + 1], u2 = col[j + 2], u3 = col[j + 3];
            float4 x0 = hin4[(size_t)u0 * S4 + t];
            float4 x1 = hin4[(size_t)u1 * S4 + t];
            float4 x2 = hin4[(size_t)u2 * S4 + t];
            float4 x3 = hin4[(size_t)u3 * S4 + t];
            a0.x += x0.x; a0.y += x0.y; a0.z += x0.z; a0.w += x0.w;
            a1.x += x1.x; a1.y += x1.y; a1.z += x1.z; a1.w += x1.w;
            a2.x += x2.x; a2.y += x2.y; a2.z += x2.z; a2.w += x2.w;
            a3.x += x3.x; a3.y += x3.y; a3.z += x3.z; a3.w += x3.w;
        }
        for (; j < r1; ++j) {
            int u = col[j];
            float4 x = hin4[(size_t)u * S4 + t];
            a0.x += x.x; a0.y += x.y; a0.z += x.z; a0.w += x.w;
        }
        float4 sx = hin4[(size_t)v * S4 + t];
        float inv = 1.0f / (float)(r1 - r0 + 1);
        float4 acc;
        acc.x = ((a0.x + a1.x) + (a2.x + a3.x) + sx.x) * inv;
        acc.y = ((a0.y + a1.y) + (a2.y + a3.y) + sx.y) * inv;
        acc.z = ((a0.z + a1.z) + (a2.z + a3.z) + sx.z) * inv;
        acc.w = ((a0.w + a1.w) + (a2.w + a3.w) + sx.w) * inv;
        sH[sub][t * 4 + 0] = acc.x;
        sH[sub][t * 4 + 1] = acc.y;
        sH[sub][t * 4 + 2] = acc.z;
        sH[sub][t * 4 + 3] = acc.w;
    }
    __syncthreads();
    if (v < n) {
        int o0 = t * OPT;
        float accO[OPT];
#pragma unroll
        for (int i = 0; i < OPT; ++i) accO[i] = sB[o0 + i];
#pragma unroll 4
        for (int k = 0; k < DIN; ++k) {
            float hk = sH[sub][k];
#pragma unroll
            for (int i = 0; i < OPT; ++i) accO[i] += hk * sW[k * DOUT + o0 + i];
        }
#pragma unroll
        for (int i = 0; i < OPT; i += 4) {
            float4 r;
            r.x = fmaxf(accO[i + 0], 0.f);
            r.y = fmaxf(accO[i + 1], 0.f);
            r.z = fmaxf(accO[i + 2], 0.f);
            r.w = fmaxf(accO[i + 3], 0.f);
            *reinterpret_cast<float4*>(hout + (size_t)v * DOUT + o0 + i) = r;
        }
    }
}

// ---------------- Pooling: per-graph mean over sorted graph_ids ----------------

__device__ __forceinline__ int lower_bound_i(const int* __restrict__ a, int n, int key) {
    int lo = 0, hi = n;
    while (lo < hi) {
        int m = (lo + hi) >> 1;
        if (a[m] < key) lo = m + 1; else hi = m;
    }
    return lo;
}

__global__ __launch_bounds__(256) void pool_kernel(const float* __restrict__ h,
                                                   const int* __restrict__ gids,
                                                   float* __restrict__ out, int n) {
    int bx = blockIdx.x;
    int g = bx >> 3, s = bx & 7;
    int start = lower_bound_i(gids, n, g);
    int end = lower_bound_i(gids, n, g + 1);
    int len = end - start;
    float inv = 1.0f / (float)(len > 0 ? len : 1);
    int chunk = (len + 7) / 8;
    int s0 = start + s * chunk;
    int s1 = min(s0 + chunk, end);
    int t = threadIdx.x;
    int d = t & 63, j = t >> 6;
    float acc = 0.f;
    for (int i = s0 + j; i < s1; i += 4) acc += h[(size_t)i * 64 + d];
    __shared__ float red[4][64];
    red[j][d] = acc;
    __syncthreads();
    if (j == 0) {
        float tot = (red[0][d] + red[1][d]) + (red[2][d] + red[3][d]);
        atomicAdd(&out[g * 64 + d], tot * inv);
    }
}

// ---------------- launch ----------------

extern "C" void kernel_launch(void* const* d_in, const int* in_sizes, int n_in,
                              void* d_out, int out_size, void* d_ws, size_t ws_size,
                              hipStream_t stream) {
    const int N = N_NODES, E = N_EDGES;
    const float* feat = (const float*)d_in[0];
    const int* src = (const int*)d_in[1];
    const int* dst = (const int*)d_in[2];
    const int* gids = (const int*)d_in[3];
    const float* W1 = (const float*)d_in[4];
    const float* b1 = (const float*)d_in[5];
    const float* W2 = (const float*)d_in[6];
    const float* b2 = (const float*)d_in[7];
    const float* W3 = (const float*)d_in[8];
    const float* b3 = (const float*)d_in[9];
    const float* W4 = (const float*)d_in[10];
    const float* b4 = (const float*)d_in[11];
    float* out = (float*)d_out;

    // workspace layout
    int* deg = (int*)d_ws;            // N
    int* rp = deg + N;                // N+1
    int* cur = rp + N + 1;            // N
    int* partials = cur + N;          // 128
    int* col = partials + 128;        // E
    size_t off = (size_t)((char*)(col + E) - (char*)d_ws);
    off = (off + 15) & ~(size_t)15;
    float* h0 = (float*)((char*)d_ws + off);  // N*64
    float* h1 = h0 + (size_t)N * 64;          // N*64

    hipMemsetAsync(deg, 0, (size_t)N * sizeof(int), stream);
    hipMemsetAsync(out, 0, (size_t)N_GRAPHS * 64 * sizeof(float), stream);

    deg_kernel<<<(E + 255) / 256, 256, 0, stream>>>(dst, deg, E);
    const int NB = (N + 1023) / 1024;  // 98
    scan_partial<<<NB, 256, 0, stream>>>(deg, partials, N);
    scan_total<<<1, 64, 0, stream>>>(partials, NB);
    scan_write<<<NB, 256, 0, stream>>>(deg, partials, rp, cur, N, E);
    csr_fill_part<<<8 * 256, 256, 0, stream>>>(src, dst, cur, col, E);

    sage_layer1<<<(N + 255) / 256, 256, 0, stream>>>(feat, rp, col, W1, b1, h0, N);
    sage_layer<16, 32><<<(N + 63) / 64, 256, 0, stream>>>(h0, rp, col, W2, b2, h1, N);
    sage_layer<32, 64><<<(N + 31) / 32, 256, 0, stream>>>(h1, rp, col, W3, b3, h0, N);
    sage_layer<64, 64><<<(N + 15) / 16, 256, 0, stream>>>(h0, rp, col, W4, b4, h1, N);

    pool_kernel<<<N_GRAPHS * 8, 256, 0, stream>>>(h1, gids, out, N);
}

// Round 3
// 305.978 us; speedup vs baseline: 1.5002x; 1.2283x over previous
//
#include <hip/hip_runtime.h>
#include <hip/hip_bf16.h>

#define N_NODES 100000
#define N_EDGES 1600000
#define N_GRAPHS 64

// ---------------- bf16 helpers (RNE, values are finite post-relu) ----------------

__device__ __forceinline__ unsigned int f2bf(float f) {
    unsigned int u = __float_as_uint(f);
    return (u + 0x7fffu + ((u >> 16) & 1u)) >> 16;
}
__device__ __forceinline__ float bf_lo(unsigned int w) { return __uint_as_float(w << 16); }
__device__ __forceinline__ float bf_hi(unsigned int w) { return __uint_as_float(w & 0xffff0000u); }

// ---------------- CSR build ----------------

// XCD-partitioned degree count: partition p only touches its 1/8 node range ->
// atomic traffic confined to a ~50KB L2-resident shard per XCD.
__global__ __launch_bounds__(256) void deg_part(const int* __restrict__ dst,
                                                int* __restrict__ deg, int E) {
    const int p = blockIdx.x & 7;
    const int c = blockIdx.x >> 3;
    const int nchunks = gridDim.x >> 3;
    const int lo = p * (N_NODES / 8);
    const int hi = (p == 7) ? N_NODES : lo + (N_NODES / 8);
    for (int e = c * 256 + threadIdx.x; e < E; e += nchunks * 256) {
        int v = dst[e];
        if (v >= lo && v < hi) atomicAdd(&deg[v], 1);
    }
}

// Block b sums deg[b*1024 .. b*1024+1023] -> partials[b]
__global__ __launch_bounds__(256) void scan_partial(const int* __restrict__ deg,
                                                    int* __restrict__ partials, int n) {
    __shared__ int s[256];
    int b = blockIdx.x, t = threadIdx.x;
    int base = b * 1024;
    int sum = 0;
#pragma unroll
    for (int i = 0; i < 4; ++i) {
        int idx = base + i * 256 + t;
        if (idx < n) sum += deg[idx];
    }
    s[t] = sum;
    __syncthreads();
    for (int o = 128; o > 0; o >>= 1) {
        if (t < o) s[t] += s[t + o];
        __syncthreads();
    }
    if (t == 0) partials[b] = s[0];
}

__global__ void scan_total(int* partials, int nb) {
    if (threadIdx.x == 0 && blockIdx.x == 0) {
        int run = 0;
        for (int i = 0; i < nb; ++i) {
            int v = partials[i];
            partials[i] = run;
            run += v;
        }
    }
}

__global__ __launch_bounds__(256) void scan_write(const int* __restrict__ deg,
                                                  const int* __restrict__ partials,
                                                  int* __restrict__ rp, int* __restrict__ cur,
                                                  int n, int E) {
    __shared__ int s[256];
    int b = blockIdx.x, t = threadIdx.x;
    int base = b * 1024 + t * 4;
    int d[4];
    int sum = 0;
#pragma unroll
    for (int i = 0; i < 4; ++i) {
        int idx = base + i;
        d[i] = (idx < n) ? deg[idx] : 0;
        sum += d[i];
    }
    s[t] = sum;
    __syncthreads();
    for (int o = 1; o < 256; o <<= 1) {
        int tmp = 0;
        if (t >= o) tmp = s[t - o];
        __syncthreads();
        s[t] += tmp;
        __syncthreads();
    }
    int running = partials[b] + (s[t] - sum);
#pragma unroll
    for (int i = 0; i < 4; ++i) {
        int idx = base + i;
        if (idx < n) {
            rp[idx] = running;
            cur[idx] = running;
            running += d[i];
        }
    }
    if (b == 0 && t == 0) rp[n] = E;
}

// XCD-partitioned fill (keeps each XCD's col write window L2-resident).
__global__ __launch_bounds__(256) void csr_fill_part(const int* __restrict__ src,
                                                     const int* __restrict__ dst,
                                                     int* __restrict__ cur,
                                                     int* __restrict__ col, int E) {
    const int p = blockIdx.x & 7;
    const int c = blockIdx.x >> 3;
    const int nchunks = gridDim.x >> 3;
    const int lo = p * (N_NODES / 8);
    const int hi = (p == 7) ? N_NODES : lo + (N_NODES / 8);
    for (int e = c * 256 + threadIdx.x; e < E; e += nchunks * 256) {
        int v = dst[e];
        if (v >= lo && v < hi) {
            int pos = atomicAdd(&cur[v], 1);
            col[pos] = src[e];
        }
    }
}

// ---------------- Layer 1 (din=6, dout=16): one thread per node, fp32 ----------------

__global__ __launch_bounds__(256) void sage_layer1(const float* __restrict__ feat,
                                                   const int* __restrict__ rp,
                                                   const int* __restrict__ col,
                                                   const float* __restrict__ W,
                                                   const float* __restrict__ bias,
                                                   float* __restrict__ hout, int n) {
    __shared__ float sW[6 * 16];
    __shared__ float sB[16];
    int tid = threadIdx.x;
    if (tid < 96) sW[tid] = W[tid];
    if (tid < 16) sB[tid] = bias[tid];
    __syncthreads();
    int v = blockIdx.x * 256 + tid;
    if (v >= n) return;
    int r0 = rp[v], r1 = rp[v + 1];
    float acc[6] = {0.f, 0.f, 0.f, 0.f, 0.f, 0.f};
    const float2* f2 = reinterpret_cast<const float2*>(feat);
    int j = r0;
    for (; j + 4 <= r1; j += 4) {
        int u0 = col[j], u1 = col[j + 1], u2 = col[j + 2], u3 = col[j + 3];
        float2 a0 = f2[u0 * 3 + 0], b0 = f2[u0 * 3 + 1], c0 = f2[u0 * 3 + 2];
        float2 a1 = f2[u1 * 3 + 0], b1 = f2[u1 * 3 + 1], c1 = f2[u1 * 3 + 2];
        float2 a2 = f2[u2 * 3 + 0], b2 = f2[u2 * 3 + 1], c2 = f2[u2 * 3 + 2];
        float2 a3 = f2[u3 * 3 + 0], b3 = f2[u3 * 3 + 1], c3 = f2[u3 * 3 + 2];
        acc[0] += (a0.x + a1.x) + (a2.x + a3.x);
        acc[1] += (a0.y + a1.y) + (a2.y + a3.y);
        acc[2] += (b0.x + b1.x) + (b2.x + b3.x);
        acc[3] += (b0.y + b1.y) + (b2.y + b3.y);
        acc[4] += (c0.x + c1.x) + (c2.x + c3.x);
        acc[5] += (c0.y + c1.y) + (c2.y + c3.y);
    }
    for (; j < r1; ++j) {
        int u = col[j];
        float2 a = f2[u * 3 + 0], b = f2[u * 3 + 1], c = f2[u * 3 + 2];
        acc[0] += a.x; acc[1] += a.y;
        acc[2] += b.x; acc[3] += b.y;
        acc[4] += c.x; acc[5] += c.y;
    }
    {
        float2 a = f2[v * 3 + 0], b = f2[v * 3 + 1], c = f2[v * 3 + 2];
        acc[0] += a.x; acc[1] += a.y;
        acc[2] += b.x; acc[3] += b.y;
        acc[4] += c.x; acc[5] += c.y;
    }
    float inv = 1.0f / (float)(r1 - r0 + 1);
#pragma unroll
    for (int k = 0; k < 6; ++k) acc[k] *= inv;
    float outv[16];
#pragma unroll
    for (int o = 0; o < 16; ++o) outv[o] = sB[o];
#pragma unroll
    for (int k = 0; k < 6; ++k) {
#pragma unroll
        for (int o = 0; o < 16; ++o) outv[o] += acc[k] * sW[k * 16 + o];
    }
    float4* ho4 = reinterpret_cast<float4*>(hout + (size_t)v * 16);
#pragma unroll
    for (int q = 0; q < 4; ++q) {
        float4 r;
        r.x = fmaxf(outv[q * 4 + 0], 0.f);
        r.y = fmaxf(outv[q * 4 + 1], 0.f);
        r.z = fmaxf(outv[q * 4 + 2], 0.f);
        r.w = fmaxf(outv[q * 4 + 3], 0.f);
        ho4[q] = r;
    }
}

// ---------------- Generic fused layer ----------------
// WPN = DIN/4 threads per node; each lane owns 4 input elems.
// INBF: gather rows stored as bf16 (uint2 = 4 elems, 8B/lane).
// OUTBF: epilogue packs outputs to bf16 RNE.

template <int DIN, int DOUT, bool INBF, bool OUTBF>
__global__ __launch_bounds__(256) void sage_u(const void* __restrict__ hin_v,
                                              const int* __restrict__ rp,
                                              const int* __restrict__ col,
                                              const float* __restrict__ W,
                                              const float* __restrict__ bias,
                                              void* __restrict__ hout_v, int n) {
    constexpr int WPN = DIN / 4;
    constexpr int NPB = 256 / WPN;
    constexpr int OPT = DOUT / WPN;
    __shared__ float sW[DIN * DOUT];
    __shared__ float sB[DOUT];
    __shared__ float sH[NPB][DIN + 1];

    int tid = threadIdx.x;
    for (int i = tid; i < DIN * DOUT; i += 256) sW[i] = W[i];
    if (tid < DOUT) sB[tid] = bias[tid];

    int sub = tid / WPN;
    int t = tid % WPN;
    int v = blockIdx.x * NPB + sub;

    const float4* hin4 = reinterpret_cast<const float4*>(hin_v);
    const uint2* hin2 = reinterpret_cast<const uint2*>(hin_v);

    auto load4 = [&](int u) -> float4 {
        if constexpr (INBF) {
            uint2 w = hin2[(size_t)u * (DIN / 4) + t];
            float4 r;
            r.x = bf_lo(w.x); r.y = bf_hi(w.x);
            r.z = bf_lo(w.y); r.w = bf_hi(w.y);
            return r;
        } else {
            return hin4[(size_t)u * (DIN / 4) + t];
        }
    };

    if (v < n) {
        int r0 = rp[v], r1 = rp[v + 1];
        float4 a0 = {0.f, 0.f, 0.f, 0.f}, a1 = {0.f, 0.f, 0.f, 0.f};
        float4 a2 = {0.f, 0.f, 0.f, 0.f}, a3 = {0.f, 0.f, 0.f, 0.f};
        int j = r0;
        for (; j + 4 <= r1; j += 4) {
            int u0 = col[j], u1 = col[j + 1], u2 = col[j + 2], u3 = col[j + 3];
            float4 x0 = load4(u0);
            float4 x1 = load4(u1);
            float4 x2 = load4(u2);
            float4 x3 = load4(u3);
            a0.x += x0.x; a0.y += x0.y; a0.z += x0.z; a0.w += x0.w;
            a1.x += x1.x; a1.y += x1.y; a1.z += x1.z; a1.w += x1.w;
            a2.x += x2.x; a2.y += x2.y; a2.z += x2.z; a2.w += x2.w;
            a3.x += x3.x; a3.y += x3.y; a3.z += x3.z; a3.w += x3.w;
        }
        for (; j < r1; ++j) {
            float4 x = load4(col[j]);
            a0.x += x.x; a0.y += x.y; a0.z += x.z; a0.w += x.w;
        }
        float4 sx = load4(v);
        float inv = 1.0f / (float)(r1 - r0 + 1);
        sH[sub][t * 4 + 0] = ((a0.x + a1.x) + (a2.x + a3.x) + sx.x) * inv;
        sH[sub][t * 4 + 1] = ((a0.y + a1.y) + (a2.y + a3.y) + sx.y) * inv;
        sH[sub][t * 4 + 2] = ((a0.z + a1.z) + (a2.z + a3.z) + sx.z) * inv;
        sH[sub][t * 4 + 3] = ((a0.w + a1.w) + (a2.w + a3.w) + sx.w) * inv;
    }
    __syncthreads();
    if (v < n) {
        int o0 = t * OPT;
        float accO[OPT];
#pragma unroll
        for (int i = 0; i < OPT; ++i) accO[i] = sB[o0 + i];
#pragma unroll 4
        for (int k = 0; k < DIN; ++k) {
            float hk = sH[sub][k];
#pragma unroll
            for (int i = 0; i < OPT; ++i) accO[i] += hk * sW[k * DOUT + o0 + i];
        }
        if constexpr (OUTBF) {
            unsigned int w[OPT / 2];
#pragma unroll
            for (int i = 0; i < OPT; i += 2) {
                unsigned int l = f2bf(fmaxf(accO[i], 0.f));
                unsigned int h = f2bf(fmaxf(accO[i + 1], 0.f));
                w[i / 2] = l | (h << 16);
            }
            unsigned int* op = reinterpret_cast<unsigned int*>(hout_v) +
                               (size_t)v * (DOUT / 2) + o0 / 2;
            if constexpr (OPT / 2 == 4) {
                *reinterpret_cast<uint4*>(op) = make_uint4(w[0], w[1], w[2], w[3]);
            } else if constexpr (OPT / 2 == 2) {
                *reinterpret_cast<uint2*>(op) = make_uint2(w[0], w[1]);
            } else {
                *op = w[0];
            }
        } else {
            float* hout = reinterpret_cast<float*>(hout_v);
#pragma unroll
            for (int i = 0; i < OPT; i += 4) {
                float4 r;
                r.x = fmaxf(accO[i + 0], 0.f);
                r.y = fmaxf(accO[i + 1], 0.f);
                r.z = fmaxf(accO[i + 2], 0.f);
                r.w = fmaxf(accO[i + 3], 0.f);
                *reinterpret_cast<float4*>(hout + (size_t)v * DOUT + o0 + i) = r;
            }
        }
    }
}

// ---------------- Pooling: per-graph mean, bf16 input ----------------

__device__ __forceinline__ int lower_bound_i(const int* __restrict__ a, int n, int key) {
    int lo = 0, hi = n;
    while (lo < hi) {
        int m = (lo + hi) >> 1;
        if (a[m] < key) lo = m + 1; else hi = m;
    }
    return lo;
}

__global__ __launch_bounds__(256) void pool_bf(const unsigned int* __restrict__ h32,
                                               const int* __restrict__ gids,
                                               float* __restrict__ out, int n) {
    int bx = blockIdx.x;
    int g = bx >> 3, s = bx & 7;
    int start = lower_bound_i(gids, n, g);
    int end = lower_bound_i(gids, n, g + 1);
    int len = end - start;
    float inv = 1.0f / (float)(len > 0 ? len : 1);
    int chunk = (len + 7) / 8;
    int s0 = start + s * chunk;
    int s1 = min(s0 + chunk, end);
    int t = threadIdx.x;
    int d = t & 31, j = t >> 5;  // word index 0..31 (elems 2d,2d+1), 8 rows in parallel
    float a0 = 0.f, a1 = 0.f;
    for (int i = s0 + j; i < s1; i += 8) {
        unsigned int w = h32[(size_t)i * 32 + d];
        a0 += bf_lo(w);
        a1 += bf_hi(w);
    }
    __shared__ float red[8][32][2];
    red[j][d][0] = a0;
    red[j][d][1] = a1;
    __syncthreads();
    if (t < 64) {
        int dd = t & 31, e = t >> 5;
        float tot = 0.f;
#pragma unroll
        for (int k = 0; k < 8; ++k) tot += red[k][dd][e];
        atomicAdd(&out[g * 64 + 2 * dd + e], tot * inv);
    }
}

// ---------------- launch ----------------

extern "C" void kernel_launch(void* const* d_in, const int* in_sizes, int n_in,
                              void* d_out, int out_size, void* d_ws, size_t ws_size,
                              hipStream_t stream) {
    const int N = N_NODES, E = N_EDGES;
    const float* feat = (const float*)d_in[0];
    const int* src = (const int*)d_in[1];
    const int* dst = (const int*)d_in[2];
    const int* gids = (const int*)d_in[3];
    const float* W1 = (const float*)d_in[4];
    const float* b1 = (const float*)d_in[5];
    const float* W2 = (const float*)d_in[6];
    const float* b2 = (const float*)d_in[7];
    const float* W3 = (const float*)d_in[8];
    const float* b3 = (const float*)d_in[9];
    const float* W4 = (const float*)d_in[10];
    const float* b4 = (const float*)d_in[11];
    float* out = (float*)d_out;

    // workspace layout
    int* deg = (int*)d_ws;            // N
    int* rp = deg + N;                // N+1
    int* cur = rp + N + 1;            // N
    int* partials = cur + N;          // 128
    int* col = partials + 128;        // E
    size_t off = (size_t)((char*)(col + E) - (char*)d_ws);
    off = (off + 255) & ~(size_t)255;
    float* h1 = (float*)((char*)d_ws + off);              // fp32 N*16
    unsigned int* h2 = (unsigned int*)(h1 + (size_t)N * 16);   // bf16 N*32 (N*16 words)
    unsigned int* h3 = h2 + (size_t)N * 16;                    // bf16 N*64 (N*32 words)
    unsigned int* h4 = h3 + (size_t)N * 32;                    // bf16 N*64 (N*32 words)

    hipMemsetAsync(deg, 0, (size_t)N * sizeof(int), stream);
    hipMemsetAsync(out, 0, (size_t)N_GRAPHS * 64 * sizeof(float), stream);

    deg_part<<<8 * 256, 256, 0, stream>>>(dst, deg, E);
    const int NB = (N + 1023) / 1024;  // 98
    scan_partial<<<NB, 256, 0, stream>>>(deg, partials, N);
    scan_total<<<1, 64, 0, stream>>>(partials, NB);
    scan_write<<<NB, 256, 0, stream>>>(deg, partials, rp, cur, N, E);
    csr_fill_part<<<8 * 256, 256, 0, stream>>>(src, dst, cur, col, E);

    sage_layer1<<<(N + 255) / 256, 256, 0, stream>>>(feat, rp, col, W1, b1, h1, N);
    // layer2: fp32 in (h1), bf16 out (h2). WPN=4, NPB=64.
    sage_u<16, 32, false, true><<<(N + 63) / 64, 256, 0, stream>>>(h1, rp, col, W2, b2, h2, N);
    // layer3: bf16 in (h2), bf16 out (h3). WPN=8, NPB=32.
    sage_u<32, 64, true, true><<<(N + 31) / 32, 256, 0, stream>>>(h2, rp, col, W3, b3, h3, N);
    // layer4: bf16 in (h3), bf16 out (h4). WPN=16, NPB=16.
    sage_u<64, 64, true, true><<<(N + 15) / 16, 256, 0, stream>>>(h3, rp, col, W4, b4, h4, N);

    pool_bf<<<N_GRAPHS * 8, 256, 0, stream>>>(h4, gids, out, N);
}

// Round 4
// 190.309 us; speedup vs baseline: 2.4120x; 1.6078x over previous
//
#include <hip/hip_runtime.h>
#include <hip/hip_bf16.h>

#define N_NODES 100000
#define N_EDGES 1600000
#define N_GRAPHS 64

#define NB_BKT 256      // node buckets for CSR build
#define NPBKT 391       // nodes per bucket (255*391=99705, last bucket 295)
#define EPB 1024        // edges per bin block
#define NBLK_BIN ((N_EDGES + EPB - 1) / EPB)  // 1563

// ---------------- bf16 helpers (RNE; values finite) ----------------

__device__ __forceinline__ unsigned int f2bf(float f) {
    unsigned int u = __float_as_uint(f);
    return (u + 0x7fffu + ((u >> 16) & 1u)) >> 16;
}
__device__ __forceinline__ float bf_lo(unsigned int w) { return __uint_as_float(w << 16); }
__device__ __forceinline__ float bf_hi(unsigned int w) { return __uint_as_float(w & 0xffff0000u); }

// ---------------- CSR build: bucket-binned, LDS-staged, no global atomics ----------------

// Pass A1: per-block 256-bucket histogram of dst.
__global__ __launch_bounds__(256) void bin_count(const int* __restrict__ dst,
                                                 int* __restrict__ cntmat, int E) {
    __shared__ int cnt[NB_BKT];
    int t = threadIdx.x;
    int e0 = blockIdx.x * EPB;
    cnt[t] = 0;
    __syncthreads();
#pragma unroll
    for (int k = 0; k < 4; ++k) {
        int e = e0 + k * 256 + t;
        if (e < E) {
            unsigned d = (unsigned)dst[e];
            atomicAdd(&cnt[d / (unsigned)NPBKT], 1);
        }
    }
    __syncthreads();
    cntmat[(size_t)blockIdx.x * NB_BKT + t] = cnt[t];
}

// Pass A2: for bucket b, exclusive-scan cntmat[:,b] over blocks; total -> gcnt[b].
__global__ __launch_bounds__(256) void bin_scan(int* __restrict__ cntmat,
                                                int* __restrict__ gcnt, int nblk) {
    __shared__ int s[256];
    int b = blockIdx.x, t = threadIdx.x;
    int running = 0;
    for (int c0 = 0; c0 < nblk; c0 += 256) {
        int idx = c0 + t;
        int v = (idx < nblk) ? cntmat[(size_t)idx * NB_BKT + b] : 0;
        s[t] = v;
        __syncthreads();
        for (int o = 1; o < 256; o <<= 1) {
            int a = (t >= o) ? s[t - o] : 0;
            __syncthreads();
            s[t] += a;
            __syncthreads();
        }
        if (idx < nblk) cntmat[(size_t)idx * NB_BKT + b] = running + s[t] - v;
        running += s[255];
        __syncthreads();
    }
    if (t == 0) gcnt[b] = running;
}

// Bucket totals -> exclusive prefix (colbase). colbase[NB_BKT] = E.
__global__ void scan256k(const int* __restrict__ gcnt, int* __restrict__ colbase) {
    __shared__ int s[256];
    int t = threadIdx.x;
    int c = gcnt[t];
    s[t] = c;
    __syncthreads();
    for (int o = 1; o < 256; o <<= 1) {
        int a = (t >= o) ? s[t - o] : 0;
        __syncthreads();
        s[t] += a;
        __syncthreads();
    }
    colbase[t] = s[t] - c;
    if (t == 255) colbase[256] = s[255];
}

// Pass A3: re-read edges, regroup by bucket in LDS, write records bucket-contiguous.
__global__ __launch_bounds__(256) void bin_write(const int* __restrict__ dst,
                                                 const int* __restrict__ src,
                                                 const int* __restrict__ cntmat,
                                                 const int* __restrict__ colbase,
                                                 uint2* __restrict__ rec, int E) {
    __shared__ int cnt[NB_BKT];
    __shared__ int lbase[NB_BKT];
    __shared__ int gofs[NB_BKT];
    __shared__ uint2 stage[EPB];
    int t = threadIdx.x;
    int e0 = blockIdx.x * EPB;
    cnt[t] = 0;
    gofs[t] = colbase[t] + cntmat[(size_t)blockIdx.x * NB_BKT + t];
    __syncthreads();
    int myb[4], mypos[4];
    unsigned myd[4], mys[4];
#pragma unroll
    for (int k = 0; k < 4; ++k) {
        int e = e0 + k * 256 + t;
        if (e < E) {
            unsigned d = (unsigned)dst[e];
            int b = (int)(d / (unsigned)NPBKT);
            myd[k] = d;
            mys[k] = (unsigned)src[e];
            myb[k] = b;
            mypos[k] = atomicAdd(&cnt[b], 1);
        } else {
            myb[k] = -1;
        }
    }
    __syncthreads();
    int c = cnt[t];
    lbase[t] = c;
    __syncthreads();
    for (int o = 1; o < 256; o <<= 1) {
        int a = (t >= o) ? lbase[t - o] : 0;
        __syncthreads();
        lbase[t] += a;
        __syncthreads();
    }
    lbase[t] = lbase[t] - c;  // exclusive (own-slot read+write, no race)
    __syncthreads();
#pragma unroll
    for (int k = 0; k < 4; ++k)
        if (myb[k] >= 0) stage[lbase[myb[k]] + mypos[k]] = make_uint2(myd[k], mys[k]);
    __syncthreads();
    int total = min(EPB, E - e0);
    for (int i = t; i < total; i += 256) {
        int lo = 0, hi = NB_BKT - 1;  // largest b with lbase[b] <= i
        while (lo < hi) {
            int m = (lo + hi + 1) >> 1;
            if (lbase[m] <= i) lo = m; else hi = m - 1;
        }
        rec[(size_t)gofs[lo] + (i - lbase[lo])] = stage[i];
    }
}

// Pass C: one workgroup per bucket. Local deg+prefix in LDS -> rp; scatter col in
// LDS; stream out coalesced (zero write amplification).
__global__ __launch_bounds__(256) void fill_bucket(const uint2* __restrict__ rec,
                                                   const int* __restrict__ colbase,
                                                   int* __restrict__ rp,
                                                   int* __restrict__ col, int n) {
    __shared__ int sdeg[512];
    __shared__ int lcur[512];
    __shared__ int lcol[8192];  // 32 KB; bucket edges mean 6250, +24 sigma head
    int p = blockIdx.x, t = threadIdx.x;
    int nbase = p * NPBKT;
    int nn = min(NPBKT, n - nbase);
    int cbase = colbase[p];
    int cnt = colbase[p + 1] - cbase;
    sdeg[t] = 0;
    sdeg[t + 256] = 0;
    __syncthreads();
    const uint2* r = rec + cbase;
    for (int i = t; i < cnt; i += 256) atomicAdd(&sdeg[r[i].x - (unsigned)nbase], 1);
    __syncthreads();
    int c0 = sdeg[t], c1 = sdeg[t + 256];
    for (int o = 1; o < 512; o <<= 1) {
        int a = (t >= o) ? sdeg[t - o] : 0;
        int b = (t + 256 >= o) ? sdeg[t + 256 - o] : 0;
        __syncthreads();
        sdeg[t] += a;
        sdeg[t + 256] += b;
        __syncthreads();
    }
    int ex0 = sdeg[t] - c0, ex1 = sdeg[t + 256] - c1;
    lcur[t] = ex0;
    lcur[t + 256] = ex1;
    if (t < nn) rp[nbase + t] = cbase + ex0;
    if (t + 256 < nn) rp[nbase + t + 256] = cbase + ex1;
    if (p == NB_BKT - 1 && t == 0) rp[n] = cbase + cnt;
    __syncthreads();
    for (int i = t; i < cnt; i += 256) {
        uint2 e = r[i];
        int slot = atomicAdd(&lcur[e.x - (unsigned)nbase], 1);
        lcol[slot] = (int)e.y;
    }
    __syncthreads();
    for (int i = t; i < cnt; i += 256) col[cbase + i] = lcol[i];
}

// ---------------- Layer 1 (din=6, dout=16): one thread per node, bf16 out ----------------

__global__ __launch_bounds__(256) void sage_layer1(const float* __restrict__ feat,
                                                   const int* __restrict__ rp,
                                                   const int* __restrict__ col,
                                                   const float* __restrict__ W,
                                                   const float* __restrict__ bias,
                                                   unsigned int* __restrict__ hout, int n) {
    __shared__ float sW[6 * 16];
    __shared__ float sB[16];
    int tid = threadIdx.x;
    if (tid < 96) sW[tid] = W[tid];
    if (tid < 16) sB[tid] = bias[tid];
    __syncthreads();
    int v = blockIdx.x * 256 + tid;
    if (v >= n) return;
    int r0 = rp[v], r1 = rp[v + 1];
    float acc[6] = {0.f, 0.f, 0.f, 0.f, 0.f, 0.f};
    const float2* f2 = reinterpret_cast<const float2*>(feat);
    int j = r0;
    for (; j + 4 <= r1; j += 4) {
        int u0 = col[j], u1 = col[j + 1], u2 = col[j + 2], u3 = col[j + 3];
        float2 a0 = f2[u0 * 3 + 0], b0 = f2[u0 * 3 + 1], c0 = f2[u0 * 3 + 2];
        float2 a1 = f2[u1 * 3 + 0], b1 = f2[u1 * 3 + 1], c1 = f2[u1 * 3 + 2];
        float2 a2 = f2[u2 * 3 + 0], b2 = f2[u2 * 3 + 1], c2 = f2[u2 * 3 + 2];
        float2 a3 = f2[u3 * 3 + 0], b3 = f2[u3 * 3 + 1], c3 = f2[u3 * 3 + 2];
        acc[0] += (a0.x + a1.x) + (a2.x + a3.x);
        acc[1] += (a0.y + a1.y) + (a2.y + a3.y);
        acc[2] += (b0.x + b1.x) + (b2.x + b3.x);
        acc[3] += (b0.y + b1.y) + (b2.y + b3.y);
        acc[4] += (c0.x + c1.x) + (c2.x + c3.x);
        acc[5] += (c0.y + c1.y) + (c2.y + c3.y);
    }
    for (; j < r1; ++j) {
        int u = col[j];
        float2 a = f2[u * 3 + 0], b = f2[u * 3 + 1], c = f2[u * 3 + 2];
        acc[0] += a.x; acc[1] += a.y;
        acc[2] += b.x; acc[3] += b.y;
        acc[4] += c.x; acc[5] += c.y;
    }
    {
        float2 a = f2[v * 3 + 0], b = f2[v * 3 + 1], c = f2[v * 3 + 2];
        acc[0] += a.x; acc[1] += a.y;
        acc[2] += b.x; acc[3] += b.y;
        acc[4] += c.x; acc[5] += c.y;
    }
    float inv = 1.0f / (float)(r1 - r0 + 1);
#pragma unroll
    for (int k = 0; k < 6; ++k) acc[k] *= inv;
    float outv[16];
#pragma unroll
    for (int o = 0; o < 16; ++o) outv[o] = sB[o];
#pragma unroll
    for (int k = 0; k < 6; ++k) {
#pragma unroll
        for (int o = 0; o < 16; ++o) outv[o] += acc[k] * sW[k * 16 + o];
    }
    unsigned int w[8];
#pragma unroll
    for (int o = 0; o < 16; o += 2) {
        unsigned int l = f2bf(fmaxf(outv[o], 0.f));
        unsigned int h = f2bf(fmaxf(outv[o + 1], 0.f));
        w[o / 2] = l | (h << 16);
    }
    uint4* op = reinterpret_cast<uint4*>(hout + (size_t)v * 8);
    op[0] = make_uint4(w[0], w[1], w[2], w[3]);
    op[1] = make_uint4(w[4], w[5], w[6], w[7]);
}

// ---------------- Generic fused layer ----------------

template <int DIN, int DOUT, bool INBF, bool OUTBF>
__global__ __launch_bounds__(256) void sage_u(const void* __restrict__ hin_v,
                                              const int* __restrict__ rp,
                                              const int* __restrict__ col,
                                              const float* __restrict__ W,
                                              const float* __restrict__ bias,
                                              void* __restrict__ hout_v, int n) {
    constexpr int WPN = DIN / 4;
    constexpr int NPB = 256 / WPN;
    constexpr int OPT = DOUT / WPN;
    __shared__ float sW[DIN * DOUT];
    __shared__ float sB[DOUT];
    __shared__ float sH[NPB][DIN + 1];

    int tid = threadIdx.x;
    for (int i = tid; i < DIN * DOUT; i += 256) sW[i] = W[i];
    if (tid < DOUT) sB[tid] = bias[tid];

    int sub = tid / WPN;
    int t = tid % WPN;
    int v = blockIdx.x * NPB + sub;

    const float4* hin4 = reinterpret_cast<const float4*>(hin_v);
    const uint2* hin2 = reinterpret_cast<const uint2*>(hin_v);

    auto load4 = [&](int u) -> float4 {
        if constexpr (INBF) {
            uint2 w = hin2[(size_t)u * (DIN / 4) + t];
            float4 r;
            r.x = bf_lo(w.x); r.y = bf_hi(w.x);
            r.z = bf_lo(w.y); r.w = bf_hi(w.y);
            return r;
        } else {
            return hin4[(size_t)u * (DIN / 4) + t];
        }
    };

    if (v < n) {
        int r0 = rp[v], r1 = rp[v + 1];
        float4 a0 = {0.f, 0.f, 0.f, 0.f}, a1 = {0.f, 0.f, 0.f, 0.f};
        float4 a2 = {0.f, 0.f, 0.f, 0.f}, a3 = {0.f, 0.f, 0.f, 0.f};
        int j = r0;
        for (; j + 4 <= r1; j += 4) {
            int u0 = col[j], u1 = col[j + 1], u2 = col[j + 2], u3 = col[j + 3];
            float4 x0 = load4(u0);
            float4 x1 = load4(u1);
            float4 x2 = load4(u2);
            float4 x3 = load4(u3);
            a0.x += x0.x; a0.y += x0.y; a0.z += x0.z; a0.w += x0.w;
            a1.x += x1.x; a1.y += x1.y; a1.z += x1.z; a1.w += x1.w;
            a2.x += x2.x; a2.y += x2.y; a2.z += x2.z; a2.w += x2.w;
            a3.x += x3.x; a3.y += x3.y; a3.z += x3.z; a3.w += x3.w;
        }
        for (; j < r1; ++j) {
            float4 x = load4(col[j]);
            a0.x += x.x; a0.y += x.y; a0.z += x.z; a0.w += x.w;
        }
        float4 sx = load4(v);
        float inv = 1.0f / (float)(r1 - r0 + 1);
        sH[sub][t * 4 + 0] = ((a0.x + a1.x) + (a2.x + a3.x) + sx.x) * inv;
        sH[sub][t * 4 + 1] = ((a0.y + a1.y) + (a2.y + a3.y) + sx.y) * inv;
        sH[sub][t * 4 + 2] = ((a0.z + a1.z) + (a2.z + a3.z) + sx.z) * inv;
        sH[sub][t * 4 + 3] = ((a0.w + a1.w) + (a2.w + a3.w) + sx.w) * inv;
    }
    __syncthreads();
    if (v < n) {
        int o0 = t * OPT;
        float accO[OPT];
#pragma unroll
        for (int i = 0; i < OPT; ++i) accO[i] = sB[o0 + i];
#pragma unroll 4
        for (int k = 0; k < DIN; ++k) {
            float hk = sH[sub][k];
#pragma unroll
            for (int i = 0; i < OPT; ++i) accO[i] += hk * sW[k * DOUT + o0 + i];
        }
        if constexpr (OUTBF) {
            unsigned int w[OPT / 2];
#pragma unroll
            for (int i = 0; i < OPT; i += 2) {
                unsigned int l = f2bf(fmaxf(accO[i], 0.f));
                unsigned int h = f2bf(fmaxf(accO[i + 1], 0.f));
                w[i / 2] = l | (h << 16);
            }
            unsigned int* op = reinterpret_cast<unsigned int*>(hout_v) +
                               (size_t)v * (DOUT / 2) + o0 / 2;
            if constexpr (OPT / 2 == 4) {
                *reinterpret_cast<uint4*>(op) = make_uint4(w[0], w[1], w[2], w[3]);
            } else if constexpr (OPT / 2 == 2) {
                *reinterpret_cast<uint2*>(op) = make_uint2(w[0], w[1]);
            } else {
                *op = w[0];
            }
        } else {
            float* hout = reinterpret_cast<float*>(hout_v);
#pragma unroll
            for (int i = 0; i < OPT; i += 4) {
                float4 rr;
                rr.x = fmaxf(accO[i + 0], 0.f);
                rr.y = fmaxf(accO[i + 1], 0.f);
                rr.z = fmaxf(accO[i + 2], 0.f);
                rr.w = fmaxf(accO[i + 3], 0.f);
                *reinterpret_cast<float4*>(hout + (size_t)v * DOUT + o0 + i) = rr;
            }
        }
    }
}

// ---------------- Pooling: per-graph mean, bf16 input ----------------

__device__ __forceinline__ int lower_bound_i(const int* __restrict__ a, int n, int key) {
    int lo = 0, hi = n;
    while (lo < hi) {
        int m = (lo + hi) >> 1;
        if (a[m] < key) lo = m + 1; else hi = m;
    }
    return lo;
}

__global__ __launch_bounds__(256) void pool_bf(const unsigned int* __restrict__ h32,
                                               const int* __restrict__ gids,
                                               float* __restrict__ out, int n) {
    int bx = blockIdx.x;
    int g = bx >> 3, s = bx & 7;
    int start = lower_bound_i(gids, n, g);
    int end = lower_bound_i(gids, n, g + 1);
    int len = end - start;
    float inv = 1.0f / (float)(len > 0 ? len : 1);
    int chunk = (len + 7) / 8;
    int s0 = start + s * chunk;
    int s1 = min(s0 + chunk, end);
    int t = threadIdx.x;
    int d = t & 31, j = t >> 5;
    float a0 = 0.f, a1 = 0.f;
    for (int i = s0 + j; i < s1; i += 8) {
        unsigned int w = h32[(size_t)i * 32 + d];
        a0 += bf_lo(w);
        a1 += bf_hi(w);
    }
    __shared__ float red[8][32][2];
    red[j][d][0] = a0;
    red[j][d][1] = a1;
    __syncthreads();
    if (t < 64) {
        int dd = t & 31, e = t >> 5;
        float tot = 0.f;
#pragma unroll
        for (int k = 0; k < 8; ++k) tot += red[k][dd][e];
        atomicAdd(&out[g * 64 + 2 * dd + e], tot * inv);
    }
}

// ---------------- launch ----------------

extern "C" void kernel_launch(void* const* d_in, const int* in_sizes, int n_in,
                              void* d_out, int out_size, void* d_ws, size_t ws_size,
                              hipStream_t stream) {
    const int N = N_NODES, E = N_EDGES;
    const float* feat = (const float*)d_in[0];
    const int* src = (const int*)d_in[1];
    const int* dst = (const int*)d_in[2];
    const int* gids = (const int*)d_in[3];
    const float* W1 = (const float*)d_in[4];
    const float* b1 = (const float*)d_in[5];
    const float* W2 = (const float*)d_in[6];
    const float* b2 = (const float*)d_in[7];
    const float* W3 = (const float*)d_in[8];
    const float* b3 = (const float*)d_in[9];
    const float* W4 = (const float*)d_in[10];
    const float* b4 = (const float*)d_in[11];
    float* out = (float*)d_out;

    // workspace layout
    int* rp = (int*)d_ws;                       // N+1
    int* gcnt = rp + (N + 1);                   // 256
    int* colbase = gcnt + 256;                  // 257
    int* cntmat = colbase + 257;                // NBLK_BIN*256 (1.6 MB)
    int* col = cntmat + (size_t)NBLK_BIN * 256; // E
    size_t off = (size_t)((char*)(col + E) - (char*)d_ws);
    off = (off + 255) & ~(size_t)255;
    unsigned int* h1 = (unsigned int*)((char*)d_ws + off);  // bf16 N*16 (N*8 words, 3.2MB)
    unsigned int* h2 = h1 + (size_t)N * 8;                   // bf16 N*32 (6.4MB)
    unsigned int* h3 = h2 + (size_t)N * 16;                  // bf16 N*64 (12.8MB)
    unsigned int* h4 = h3 + (size_t)N * 32;                  // bf16 N*64 (12.8MB)
    uint2* rec = (uint2*)h3;  // 12.8MB edge records; dead before layer-3 writes h3

    hipMemsetAsync(out, 0, (size_t)N_GRAPHS * 64 * sizeof(float), stream);

    bin_count<<<NBLK_BIN, 256, 0, stream>>>(dst, cntmat, E);
    bin_scan<<<NB_BKT, 256, 0, stream>>>(cntmat, gcnt, NBLK_BIN);
    scan256k<<<1, 256, 0, stream>>>(gcnt, colbase);
    bin_write<<<NBLK_BIN, 256, 0, stream>>>(dst, src, cntmat, colbase, rec, E);
    fill_bucket<<<NB_BKT, 256, 0, stream>>>(rec, colbase, rp, col, N);

    sage_layer1<<<(N + 255) / 256, 256, 0, stream>>>(feat, rp, col, W1, b1, h1, N);
    sage_u<16, 32, true, true><<<(N + 63) / 64, 256, 0, stream>>>(h1, rp, col, W2, b2, h2, N);
    sage_u<32, 64, true, true><<<(N + 31) / 32, 256, 0, stream>>>(h2, rp, col, W3, b3, h3, N);
    sage_u<64, 64, true, true><<<(N + 15) / 16, 256, 0, stream>>>(h3, rp, col, W4, b4, h4, N);

    pool_bf<<<N_GRAPHS * 8, 256, 0, stream>>>(h4, gids, out, N);
}

// Round 5
// 183.165 us; speedup vs baseline: 2.5061x; 1.0390x over previous
//
#include <hip/hip_runtime.h>
#include <hip/hip_bf16.h>
#include <hip/hip_fp16.h>

#define N_NODES 100000
#define N_EDGES 1600000
#define N_GRAPHS 64

#define NB_BKT 256      // node buckets for CSR build
#define NPBKT 391       // nodes per bucket (255*391=99705, last bucket 295)
#define EPB 1024        // edges per bin block
#define NBLK_BIN ((N_EDGES + EPB - 1) / EPB)  // 1563

// ---------------- f16 helpers ----------------

__device__ __forceinline__ __half2 u2h(unsigned int u) {
    return __builtin_bit_cast(__half2, u);
}
__device__ __forceinline__ float2 u2f2(unsigned int u) {
    return __half22float2(u2h(u));
}
__device__ __forceinline__ unsigned int packh2(float a, float b) {
    return __builtin_bit_cast(unsigned int, __float22half2_rn(make_float2(a, b)));
}

// ---------------- CSR build: bucket-binned, LDS-staged, no global atomics ----------------

__global__ __launch_bounds__(256) void bin_count(const int* __restrict__ dst,
                                                 int* __restrict__ cntmat, int E) {
    __shared__ int cnt[NB_BKT];
    int t = threadIdx.x;
    int e0 = blockIdx.x * EPB;
    cnt[t] = 0;
    __syncthreads();
#pragma unroll
    for (int k = 0; k < 4; ++k) {
        int e = e0 + k * 256 + t;
        if (e < E) {
            unsigned d = (unsigned)dst[e];
            atomicAdd(&cnt[d / (unsigned)NPBKT], 1);
        }
    }
    __syncthreads();
    cntmat[(size_t)blockIdx.x * NB_BKT + t] = cnt[t];
}

__global__ __launch_bounds__(256) void bin_scan(int* __restrict__ cntmat,
                                                int* __restrict__ gcnt, int nblk) {
    __shared__ int s[256];
    int b = blockIdx.x, t = threadIdx.x;
    int running = 0;
    for (int c0 = 0; c0 < nblk; c0 += 256) {
        int idx = c0 + t;
        int v = (idx < nblk) ? cntmat[(size_t)idx * NB_BKT + b] : 0;
        s[t] = v;
        __syncthreads();
        for (int o = 1; o < 256; o <<= 1) {
            int a = (t >= o) ? s[t - o] : 0;
            __syncthreads();
            s[t] += a;
            __syncthreads();
        }
        if (idx < nblk) cntmat[(size_t)idx * NB_BKT + b] = running + s[t] - v;
        running += s[255];
        __syncthreads();
    }
    if (t == 0) gcnt[b] = running;
}

__global__ void scan256k(const int* __restrict__ gcnt, int* __restrict__ colbase) {
    __shared__ int s[256];
    int t = threadIdx.x;
    int c = gcnt[t];
    s[t] = c;
    __syncthreads();
    for (int o = 1; o < 256; o <<= 1) {
        int a = (t >= o) ? s[t - o] : 0;
        __syncthreads();
        s[t] += a;
        __syncthreads();
    }
    colbase[t] = s[t] - c;
    if (t == 255) colbase[256] = s[255];
}

__global__ __launch_bounds__(256) void bin_write(const int* __restrict__ dst,
                                                 const int* __restrict__ src,
                                                 const int* __restrict__ cntmat,
                                                 const int* __restrict__ colbase,
                                                 uint2* __restrict__ rec, int E) {
    __shared__ int cnt[NB_BKT];
    __shared__ int lbase[NB_BKT];
    __shared__ int gofs[NB_BKT];
    __shared__ uint2 stage[EPB];
    int t = threadIdx.x;
    int e0 = blockIdx.x * EPB;
    cnt[t] = 0;
    gofs[t] = colbase[t] + cntmat[(size_t)blockIdx.x * NB_BKT + t];
    __syncthreads();
    int myb[4], mypos[4];
    unsigned myd[4], mys[4];
#pragma unroll
    for (int k = 0; k < 4; ++k) {
        int e = e0 + k * 256 + t;
        if (e < E) {
            unsigned d = (unsigned)dst[e];
            int b = (int)(d / (unsigned)NPBKT);
            myd[k] = d;
            mys[k] = (unsigned)src[e];
            myb[k] = b;
            mypos[k] = atomicAdd(&cnt[b], 1);
        } else {
            myb[k] = -1;
        }
    }
    __syncthreads();
    int c = cnt[t];
    lbase[t] = c;
    __syncthreads();
    for (int o = 1; o < 256; o <<= 1) {
        int a = (t >= o) ? lbase[t - o] : 0;
        __syncthreads();
        lbase[t] += a;
        __syncthreads();
    }
    lbase[t] = lbase[t] - c;
    __syncthreads();
#pragma unroll
    for (int k = 0; k < 4; ++k)
        if (myb[k] >= 0) stage[lbase[myb[k]] + mypos[k]] = make_uint2(myd[k], mys[k]);
    __syncthreads();
    int total = min(EPB, E - e0);
    for (int i = t; i < total; i += 256) {
        int lo = 0, hi = NB_BKT - 1;
        while (lo < hi) {
            int m = (lo + hi + 1) >> 1;
            if (lbase[m] <= i) lo = m; else hi = m - 1;
        }
        rec[(size_t)gofs[lo] + (i - lbase[lo])] = stage[i];
    }
}

__global__ __launch_bounds__(256) void fill_bucket(const uint2* __restrict__ rec,
                                                   const int* __restrict__ colbase,
                                                   int* __restrict__ rp,
                                                   int* __restrict__ col, int n) {
    __shared__ int sdeg[512];
    __shared__ int lcur[512];
    __shared__ int lcol[8192];
    int p = blockIdx.x, t = threadIdx.x;
    int nbase = p * NPBKT;
    int nn = min(NPBKT, n - nbase);
    int cbase = colbase[p];
    int cnt = colbase[p + 1] - cbase;
    sdeg[t] = 0;
    sdeg[t + 256] = 0;
    __syncthreads();
    const uint2* r = rec + cbase;
    for (int i = t; i < cnt; i += 256) atomicAdd(&sdeg[r[i].x - (unsigned)nbase], 1);
    __syncthreads();
    int c0 = sdeg[t], c1 = sdeg[t + 256];
    for (int o = 1; o < 512; o <<= 1) {
        int a = (t >= o) ? sdeg[t - o] : 0;
        int b = (t + 256 >= o) ? sdeg[t + 256 - o] : 0;
        __syncthreads();
        sdeg[t] += a;
        sdeg[t + 256] += b;
        __syncthreads();
    }
    int ex0 = sdeg[t] - c0, ex1 = sdeg[t + 256] - c1;
    lcur[t] = ex0;
    lcur[t + 256] = ex1;
    if (t < nn) rp[nbase + t] = cbase + ex0;
    if (t + 256 < nn) rp[nbase + t + 256] = cbase + ex1;
    if (p == NB_BKT - 1 && t == 0) rp[n] = cbase + cnt;
    __syncthreads();
    for (int i = t; i < cnt; i += 256) {
        uint2 e = r[i];
        int slot = atomicAdd(&lcur[e.x - (unsigned)nbase], 1);
        lcol[slot] = (int)e.y;
    }
    __syncthreads();
    for (int i = t; i < cnt; i += 256) col[cbase + i] = lcol[i];
}

// ---------------- Layer 1 (din=6, dout=16): one thread per node, fp32 in, f16 out ----------------

__global__ __launch_bounds__(256) void sage_layer1(const float* __restrict__ feat,
                                                   const int* __restrict__ rp,
                                                   const int* __restrict__ col,
                                                   const float* __restrict__ W,
                                                   const float* __restrict__ bias,
                                                   unsigned int* __restrict__ hout, int n) {
    __shared__ float sW[6 * 16];
    __shared__ float sB[16];
    int tid = threadIdx.x;
    if (tid < 96) sW[tid] = W[tid];
    if (tid < 16) sB[tid] = bias[tid];
    __syncthreads();
    int v = blockIdx.x * 256 + tid;
    if (v >= n) return;
    int r0 = rp[v], r1 = rp[v + 1];
    float acc[6] = {0.f, 0.f, 0.f, 0.f, 0.f, 0.f};
    const float2* f2 = reinterpret_cast<const float2*>(feat);
    int j = r0;
    for (; j + 4 <= r1; j += 4) {
        int u0 = col[j], u1 = col[j + 1], u2 = col[j + 2], u3 = col[j + 3];
        float2 a0 = f2[u0 * 3 + 0], b0 = f2[u0 * 3 + 1], c0 = f2[u0 * 3 + 2];
        float2 a1 = f2[u1 * 3 + 0], b1 = f2[u1 * 3 + 1], c1 = f2[u1 * 3 + 2];
        float2 a2 = f2[u2 * 3 + 0], b2 = f2[u2 * 3 + 1], c2 = f2[u2 * 3 + 2];
        float2 a3 = f2[u3 * 3 + 0], b3 = f2[u3 * 3 + 1], c3 = f2[u3 * 3 + 2];
        acc[0] += (a0.x + a1.x) + (a2.x + a3.x);
        acc[1] += (a0.y + a1.y) + (a2.y + a3.y);
        acc[2] += (b0.x + b1.x) + (b2.x + b3.x);
        acc[3] += (b0.y + b1.y) + (b2.y + b3.y);
        acc[4] += (c0.x + c1.x) + (c2.x + c3.x);
        acc[5] += (c0.y + c1.y) + (c2.y + c3.y);
    }
    for (; j < r1; ++j) {
        int u = col[j];
        float2 a = f2[u * 3 + 0], b = f2[u * 3 + 1], c = f2[u * 3 + 2];
        acc[0] += a.x; acc[1] += a.y;
        acc[2] += b.x; acc[3] += b.y;
        acc[4] += c.x; acc[5] += c.y;
    }
    {
        float2 a = f2[v * 3 + 0], b = f2[v * 3 + 1], c = f2[v * 3 + 2];
        acc[0] += a.x; acc[1] += a.y;
        acc[2] += b.x; acc[3] += b.y;
        acc[4] += c.x; acc[5] += c.y;
    }
    float inv = 1.0f / (float)(r1 - r0 + 1);
#pragma unroll
    for (int k = 0; k < 6; ++k) acc[k] *= inv;
    float outv[16];
#pragma unroll
    for (int o = 0; o < 16; ++o) outv[o] = sB[o];
#pragma unroll
    for (int k = 0; k < 6; ++k) {
#pragma unroll
        for (int o = 0; o < 16; ++o) outv[o] += acc[k] * sW[k * 16 + o];
    }
    unsigned int w[8];
#pragma unroll
    for (int o = 0; o < 16; o += 2)
        w[o / 2] = packh2(fmaxf(outv[o], 0.f), fmaxf(outv[o + 1], 0.f));
    uint4* op = reinterpret_cast<uint4*>(hout + v * 8);
    op[0] = make_uint4(w[0], w[1], w[2], w[3]);
    op[1] = make_uint4(w[4], w[5], w[6], w[7]);
}

// ---------------- Generic fused layer, f16 in/out, packed f16 accumulation ----------------
// WPN = DIN/8 lanes per node; each lane loads one uint4 (8 f16) per edge.

template <int DIN, int DOUT>
__global__ __launch_bounds__(256) void sage_f16(const uint4* __restrict__ hin,
                                                const int* __restrict__ rp,
                                                const int* __restrict__ col,
                                                const float* __restrict__ W,
                                                const float* __restrict__ bias,
                                                unsigned int* __restrict__ hout, int n) {
    constexpr int WPN = DIN / 8;
    constexpr int NPB = 256 / WPN;
    constexpr int OPT = DOUT / WPN;
    __shared__ float sW[DIN * DOUT];
    __shared__ float sB[DOUT];
    __shared__ float sH[NPB][DIN + 1];

    int tid = threadIdx.x;
    for (int i = tid; i < DIN * DOUT; i += 256) sW[i] = W[i];
    if (tid < DOUT) sB[tid] = bias[tid];

    int sub = tid / WPN;
    int t = tid % WPN;
    int v = blockIdx.x * NPB + sub;

    if (v < n) {
        int r0 = rp[v], r1 = rp[v + 1];
        const __half2 z = __float2half2_rn(0.f);
        __half2 a0[4] = {z, z, z, z}, a1[4] = {z, z, z, z};
        __half2 a2[4] = {z, z, z, z}, a3[4] = {z, z, z, z};
        int j = r0;
        for (; j + 4 <= r1; j += 4) {
            int u0 = col[j], u1 = col[j + 1], u2 = col[j + 2], u3 = col[j + 3];
            uint4 w0 = hin[u0 * WPN + t];
            uint4 w1 = hin[u1 * WPN + t];
            uint4 w2 = hin[u2 * WPN + t];
            uint4 w3 = hin[u3 * WPN + t];
            a0[0] = __hadd2(a0[0], u2h(w0.x)); a0[1] = __hadd2(a0[1], u2h(w0.y));
            a0[2] = __hadd2(a0[2], u2h(w0.z)); a0[3] = __hadd2(a0[3], u2h(w0.w));
            a1[0] = __hadd2(a1[0], u2h(w1.x)); a1[1] = __hadd2(a1[1], u2h(w1.y));
            a1[2] = __hadd2(a1[2], u2h(w1.z)); a1[3] = __hadd2(a1[3], u2h(w1.w));
            a2[0] = __hadd2(a2[0], u2h(w2.x)); a2[1] = __hadd2(a2[1], u2h(w2.y));
            a2[2] = __hadd2(a2[2], u2h(w2.z)); a2[3] = __hadd2(a2[3], u2h(w2.w));
            a3[0] = __hadd2(a3[0], u2h(w3.x)); a3[1] = __hadd2(a3[1], u2h(w3.y));
            a3[2] = __hadd2(a3[2], u2h(w3.z)); a3[3] = __hadd2(a3[3], u2h(w3.w));
        }
        for (; j < r1; ++j) {
            uint4 w = hin[col[j] * WPN + t];
            a0[0] = __hadd2(a0[0], u2h(w.x)); a0[1] = __hadd2(a0[1], u2h(w.y));
            a0[2] = __hadd2(a0[2], u2h(w.z)); a0[3] = __hadd2(a0[3], u2h(w.w));
        }
#pragma unroll
        for (int q = 0; q < 4; ++q)
            a0[q] = __hadd2(__hadd2(a0[q], a1[q]), __hadd2(a2[q], a3[q]));
        uint4 ws = hin[v * WPN + t];
        unsigned swd[4] = {ws.x, ws.y, ws.z, ws.w};
        float inv = 1.0f / (float)(r1 - r0 + 1);
#pragma unroll
        for (int q = 0; q < 4; ++q) {
            float2 f = __half22float2(a0[q]);
            float2 s = u2f2(swd[q]);
            sH[sub][t * 8 + 2 * q + 0] = (f.x + s.x) * inv;
            sH[sub][t * 8 + 2 * q + 1] = (f.y + s.y) * inv;
        }
    }
    __syncthreads();
    if (v < n) {
        int o0 = t * OPT;
        float accO[OPT];
#pragma unroll
        for (int i = 0; i < OPT; ++i) accO[i] = sB[o0 + i];
#pragma unroll 4
        for (int k = 0; k < DIN; ++k) {
            float hk = sH[sub][k];
#pragma unroll
            for (int i = 0; i < OPT; ++i) accO[i] += hk * sW[k * DOUT + o0 + i];
        }
        unsigned wds[OPT / 2];
#pragma unroll
        for (int i = 0; i < OPT; i += 2)
            wds[i / 2] = packh2(fmaxf(accO[i], 0.f), fmaxf(accO[i + 1], 0.f));
        unsigned* op = hout + v * (DOUT / 2) + o0 / 2;
        if constexpr (OPT / 2 == 4) {
            *reinterpret_cast<uint4*>(op) = make_uint4(wds[0], wds[1], wds[2], wds[3]);
        } else if constexpr (OPT / 2 == 8) {
            reinterpret_cast<uint4*>(op)[0] = make_uint4(wds[0], wds[1], wds[2], wds[3]);
            reinterpret_cast<uint4*>(op)[1] = make_uint4(wds[4], wds[5], wds[6], wds[7]);
        } else {
            *reinterpret_cast<uint2*>(op) = make_uint2(wds[0], wds[1]);
        }
    }
}

// ---------------- Pooling: per-graph mean, f16 input ----------------

__device__ __forceinline__ int lower_bound_i(const int* __restrict__ a, int n, int key) {
    int lo = 0, hi = n;
    while (lo < hi) {
        int m = (lo + hi) >> 1;
        if (a[m] < key) lo = m + 1; else hi = m;
    }
    return lo;
}

__global__ __launch_bounds__(256) void pool_f16(const unsigned int* __restrict__ h32,
                                                const int* __restrict__ gids,
                                                float* __restrict__ out, int n) {
    int bx = blockIdx.x;
    int g = bx >> 3, s = bx & 7;
    int start = lower_bound_i(gids, n, g);
    int end = lower_bound_i(gids, n, g + 1);
    int len = end - start;
    float inv = 1.0f / (float)(len > 0 ? len : 1);
    int chunk = (len + 7) / 8;
    int s0 = start + s * chunk;
    int s1 = min(s0 + chunk, end);
    int t = threadIdx.x;
    int d = t & 31, j = t >> 5;
    float a0 = 0.f, a1 = 0.f;
    for (int i = s0 + j; i < s1; i += 8) {
        float2 f = u2f2(h32[(size_t)i * 32 + d]);
        a0 += f.x;
        a1 += f.y;
    }
    __shared__ float red[8][32][2];
    red[j][d][0] = a0;
    red[j][d][1] = a1;
    __syncthreads();
    if (t < 64) {
        int dd = t & 31, e = t >> 5;
        float tot = 0.f;
#pragma unroll
        for (int k = 0; k < 8; ++k) tot += red[k][dd][e];
        atomicAdd(&out[g * 64 + 2 * dd + e], tot * inv);
    }
}

// ---------------- launch ----------------

extern "C" void kernel_launch(void* const* d_in, const int* in_sizes, int n_in,
                              void* d_out, int out_size, void* d_ws, size_t ws_size,
                              hipStream_t stream) {
    const int N = N_NODES, E = N_EDGES;
    const float* feat = (const float*)d_in[0];
    const int* src = (const int*)d_in[1];
    const int* dst = (const int*)d_in[2];
    const int* gids = (const int*)d_in[3];
    const float* W1 = (const float*)d_in[4];
    const float* b1 = (const float*)d_in[5];
    const float* W2 = (const float*)d_in[6];
    const float* b2 = (const float*)d_in[7];
    const float* W3 = (const float*)d_in[8];
    const float* b3 = (const float*)d_in[9];
    const float* W4 = (const float*)d_in[10];
    const float* b4 = (const float*)d_in[11];
    float* out = (float*)d_out;

    // workspace layout
    int* rp = (int*)d_ws;                       // N+1
    int* gcnt = rp + (N + 1);                   // 256
    int* colbase = gcnt + 256;                  // 257
    int* cntmat = colbase + 257;                // NBLK_BIN*256
    int* col = cntmat + (size_t)NBLK_BIN * 256; // E
    size_t off = (size_t)((char*)(col + E) - (char*)d_ws);
    off = (off + 255) & ~(size_t)255;
    unsigned int* h1 = (unsigned int*)((char*)d_ws + off);   // f16 N*16 (N*8 words)
    unsigned int* h2 = h1 + (size_t)N * 8;                   // f16 N*32 (N*16 words)
    unsigned int* h3 = h2 + (size_t)N * 16;                  // f16 N*64 (N*32 words)
    unsigned int* h4 = h3 + (size_t)N * 32;                  // f16 N*64 (N*32 words)
    uint2* rec = (uint2*)h3;  // 12.8MB edge records; dead before layer-3 writes h3

    hipMemsetAsync(out, 0, (size_t)N_GRAPHS * 64 * sizeof(float), stream);

    bin_count<<<NBLK_BIN, 256, 0, stream>>>(dst, cntmat, E);
    bin_scan<<<NB_BKT, 256, 0, stream>>>(cntmat, gcnt, NBLK_BIN);
    scan256k<<<1, 256, 0, stream>>>(gcnt, colbase);
    bin_write<<<NBLK_BIN, 256, 0, stream>>>(dst, src, cntmat, colbase, rec, E);
    fill_bucket<<<NB_BKT, 256, 0, stream>>>(rec, colbase, rp, col, N);

    sage_layer1<<<(N + 255) / 256, 256, 0, stream>>>(feat, rp, col, W1, b1, h1, N);
    // layer2: DIN=16 WPN=2 NPB=128
    sage_f16<16, 32><<<(N + 127) / 128, 256, 0, stream>>>(
        (const uint4*)h1, rp, col, W2, b2, h2, N);
    // layer3: DIN=32 WPN=4 NPB=64
    sage_f16<32, 64><<<(N + 63) / 64, 256, 0, stream>>>(
        (const uint4*)h2, rp, col, W3, b3, h3, N);
    // layer4: DIN=64 WPN=8 NPB=32
    sage_f16<64, 64><<<(N + 31) / 32, 256, 0, stream>>>(
        (const uint4*)h3, rp, col, W4, b4, h4, N);

    pool_f16<<<N_GRAPHS * 8, 256, 0, stream>>>(h4, gids, out, N);
}

// Round 6
// 176.777 us; speedup vs baseline: 2.5967x; 1.0361x over previous
//
#include <hip/hip_runtime.h>
#include <hip/hip_bf16.h>
#include <hip/hip_fp16.h>

#define N_NODES 100000
#define N_EDGES 1600000
#define N_GRAPHS 64

#define NB_BKT 256      // node buckets for CSR build
#define NPBKT 391       // nodes per bucket (255*391=99705, last bucket 295)
#define EPB 2048        // edges per bin block
#define NBLK_BIN ((N_EDGES + EPB - 1) / EPB)  // 782

// ---------------- f16 helpers ----------------

__device__ __forceinline__ __half2 u2h(unsigned int u) {
    return __builtin_bit_cast(__half2, u);
}
__device__ __forceinline__ float2 u2f2(unsigned int u) {
    return __half22float2(u2h(u));
}
__device__ __forceinline__ unsigned int packh2(float a, float b) {
    return __builtin_bit_cast(unsigned int, __float22half2_rn(make_float2(a, b)));
}

// ---------------- CSR build: bucket-binned, LDS-staged, no global atomics ----------------

__global__ __launch_bounds__(256) void bin_count(const int* __restrict__ dst,
                                                 int* __restrict__ cntmat, int E) {
    __shared__ int cnt[NB_BKT];
    int t = threadIdx.x;
    int e0 = blockIdx.x * EPB;
    cnt[t] = 0;
    __syncthreads();
#pragma unroll
    for (int k = 0; k < 8; ++k) {
        int e = e0 + k * 256 + t;
        if (e < E) {
            unsigned d = (unsigned)dst[e];
            atomicAdd(&cnt[d / (unsigned)NPBKT], 1);
        }
    }
    __syncthreads();
    cntmat[(size_t)blockIdx.x * NB_BKT + t] = cnt[t];
}

__global__ __launch_bounds__(256) void bin_scan(int* __restrict__ cntmat,
                                                int* __restrict__ gcnt, int nblk) {
    __shared__ int s[256];
    int b = blockIdx.x, t = threadIdx.x;
    int running = 0;
    for (int c0 = 0; c0 < nblk; c0 += 256) {
        int idx = c0 + t;
        int v = (idx < nblk) ? cntmat[(size_t)idx * NB_BKT + b] : 0;
        s[t] = v;
        __syncthreads();
        for (int o = 1; o < 256; o <<= 1) {
            int a = (t >= o) ? s[t - o] : 0;
            __syncthreads();
            s[t] += a;
            __syncthreads();
        }
        if (idx < nblk) cntmat[(size_t)idx * NB_BKT + b] = running + s[t] - v;
        running += s[255];
        __syncthreads();
    }
    if (t == 0) gcnt[b] = running;
}

// Regroup edges by bucket in LDS, write records bucket-contiguous.
// colbase is computed in-block from gcnt (256-entry LDS scan).
__global__ __launch_bounds__(256) void bin_write(const int* __restrict__ dst,
                                                 const int* __restrict__ src,
                                                 const int* __restrict__ cntmat,
                                                 const int* __restrict__ gcnt,
                                                 uint2* __restrict__ rec, int E) {
    __shared__ int cnt[NB_BKT];
    __shared__ int lbase[NB_BKT];
    __shared__ int gofs[NB_BKT];
    __shared__ uint2 stage[EPB];
    int t = threadIdx.x;
    int e0 = blockIdx.x * EPB;
    // inline exclusive scan of gcnt -> colbase
    int g = gcnt[t];
    lbase[t] = g;
    __syncthreads();
    for (int o = 1; o < 256; o <<= 1) {
        int a = (t >= o) ? lbase[t - o] : 0;
        __syncthreads();
        lbase[t] += a;
        __syncthreads();
    }
    gofs[t] = (lbase[t] - g) + cntmat[(size_t)blockIdx.x * NB_BKT + t];
    cnt[t] = 0;
    __syncthreads();
    int myb[8], mypos[8];
    unsigned myd[8], mys[8];
#pragma unroll
    for (int k = 0; k < 8; ++k) {
        int e = e0 + k * 256 + t;
        if (e < E) {
            unsigned d = (unsigned)dst[e];
            int b = (int)(d / (unsigned)NPBKT);
            myd[k] = d;
            mys[k] = (unsigned)src[e];
            myb[k] = b;
            mypos[k] = atomicAdd(&cnt[b], 1);
        } else {
            myb[k] = -1;
        }
    }
    __syncthreads();
    int c = cnt[t];
    lbase[t] = c;
    __syncthreads();
    for (int o = 1; o < 256; o <<= 1) {
        int a = (t >= o) ? lbase[t - o] : 0;
        __syncthreads();
        lbase[t] += a;
        __syncthreads();
    }
    lbase[t] = lbase[t] - c;
    __syncthreads();
#pragma unroll
    for (int k = 0; k < 8; ++k)
        if (myb[k] >= 0) stage[lbase[myb[k]] + mypos[k]] = make_uint2(myd[k], mys[k]);
    __syncthreads();
    int total = min(EPB, E - e0);
    for (int i = t; i < total; i += 256) {
        int lo = 0, hi = NB_BKT - 1;
        while (lo < hi) {
            int m = (lo + hi + 1) >> 1;
            if (lbase[m] <= i) lo = m; else hi = m - 1;
        }
        rec[(size_t)gofs[lo] + (i - lbase[lo])] = stage[i];
    }
}

// One workgroup per bucket: local deg+prefix -> rp; scatter col inside LDS;
// stream out coalesced. colbase computed in-block from gcnt.
__global__ __launch_bounds__(256) void fill_bucket(const uint2* __restrict__ rec,
                                                   const int* __restrict__ gcnt,
                                                   int* __restrict__ rp,
                                                   int* __restrict__ col, int n) {
    __shared__ int sdeg[512];
    __shared__ int lcur[512];
    __shared__ int sg[256];
    __shared__ int lcol[8192];
    int p = blockIdx.x, t = threadIdx.x;
    int nbase = p * NPBKT;
    int nn = min(NPBKT, n - nbase);
    // inline exclusive scan of gcnt -> cbase
    int g = gcnt[t];
    sg[t] = g;
    __syncthreads();
    for (int o = 1; o < 256; o <<= 1) {
        int a = (t >= o) ? sg[t - o] : 0;
        __syncthreads();
        sg[t] += a;
        __syncthreads();
    }
    int ex = sg[t] - g;
    __syncthreads();
    sg[t] = ex;
    __syncthreads();
    int cbase = sg[p];
    int cnt = gcnt[p];
    sdeg[t] = 0;
    sdeg[t + 256] = 0;
    __syncthreads();
    const uint2* r = rec + cbase;
    for (int i = t; i < cnt; i += 256) atomicAdd(&sdeg[r[i].x - (unsigned)nbase], 1);
    __syncthreads();
    int c0 = sdeg[t], c1 = sdeg[t + 256];
    for (int o = 1; o < 512; o <<= 1) {
        int a = (t >= o) ? sdeg[t - o] : 0;
        int b = (t + 256 >= o) ? sdeg[t + 256 - o] : 0;
        __syncthreads();
        sdeg[t] += a;
        sdeg[t + 256] += b;
        __syncthreads();
    }
    int ex0 = sdeg[t] - c0, ex1 = sdeg[t + 256] - c1;
    lcur[t] = ex0;
    lcur[t + 256] = ex1;
    if (t < nn) rp[nbase + t] = cbase + ex0;
    if (t + 256 < nn) rp[nbase + t + 256] = cbase + ex1;
    if (p == NB_BKT - 1 && t == 0) rp[n] = cbase + cnt;
    __syncthreads();
    for (int i = t; i < cnt; i += 256) {
        uint2 e = r[i];
        int slot = atomicAdd(&lcur[e.x - (unsigned)nbase], 1);
        lcol[slot] = (int)e.y;
    }
    __syncthreads();
    for (int i = t; i < cnt; i += 256) col[cbase + i] = lcol[i];
}

// ---------------- Layer 1 (din=6, dout=16): one thread per node, fp32 in, f16 out ----------------

__global__ __launch_bounds__(256) void sage_layer1(const float* __restrict__ feat,
                                                   const int* __restrict__ rp,
                                                   const int* __restrict__ col,
                                                   const float* __restrict__ W,
                                                   const float* __restrict__ bias,
                                                   unsigned int* __restrict__ hout, int n) {
    __shared__ float sW[6 * 16];
    __shared__ float sB[16];
    int tid = threadIdx.x;
    if (tid < 96) sW[tid] = W[tid];
    if (tid < 16) sB[tid] = bias[tid];
    __syncthreads();
    int v = blockIdx.x * 256 + tid;
    if (v >= n) return;
    int r0 = rp[v], r1 = rp[v + 1];
    float acc[6] = {0.f, 0.f, 0.f, 0.f, 0.f, 0.f};
    const float2* f2 = reinterpret_cast<const float2*>(feat);
    int j = r0;
    for (; j + 4 <= r1; j += 4) {
        int u0 = col[j], u1 = col[j + 1], u2 = col[j + 2], u3 = col[j + 3];
        float2 a0 = f2[u0 * 3 + 0], b0 = f2[u0 * 3 + 1], c0 = f2[u0 * 3 + 2];
        float2 a1 = f2[u1 * 3 + 0], b1 = f2[u1 * 3 + 1], c1 = f2[u1 * 3 + 2];
        float2 a2 = f2[u2 * 3 + 0], b2 = f2[u2 * 3 + 1], c2 = f2[u2 * 3 + 2];
        float2 a3 = f2[u3 * 3 + 0], b3 = f2[u3 * 3 + 1], c3 = f2[u3 * 3 + 2];
        acc[0] += (a0.x + a1.x) + (a2.x + a3.x);
        acc[1] += (a0.y + a1.y) + (a2.y + a3.y);
        acc[2] += (b0.x + b1.x) + (b2.x + b3.x);
        acc[3] += (b0.y + b1.y) + (b2.y + b3.y);
        acc[4] += (c0.x + c1.x) + (c2.x + c3.x);
        acc[5] += (c0.y + c1.y) + (c2.y + c3.y);
    }
    for (; j < r1; ++j) {
        int u = col[j];
        float2 a = f2[u * 3 + 0], b = f2[u * 3 + 1], c = f2[u * 3 + 2];
        acc[0] += a.x; acc[1] += a.y;
        acc[2] += b.x; acc[3] += b.y;
        acc[4] += c.x; acc[5] += c.y;
    }
    {
        float2 a = f2[v * 3 + 0], b = f2[v * 3 + 1], c = f2[v * 3 + 2];
        acc[0] += a.x; acc[1] += a.y;
        acc[2] += b.x; acc[3] += b.y;
        acc[4] += c.x; acc[5] += c.y;
    }
    float inv = 1.0f / (float)(r1 - r0 + 1);
#pragma unroll
    for (int k = 0; k < 6; ++k) acc[k] *= inv;
    float outv[16];
#pragma unroll
    for (int o = 0; o < 16; ++o) outv[o] = sB[o];
#pragma unroll
    for (int k = 0; k < 6; ++k) {
#pragma unroll
        for (int o = 0; o < 16; ++o) outv[o] += acc[k] * sW[k * 16 + o];
    }
    unsigned int w[8];
#pragma unroll
    for (int o = 0; o < 16; o += 2)
        w[o / 2] = packh2(fmaxf(outv[o], 0.f), fmaxf(outv[o + 1], 0.f));
    uint4* op = reinterpret_cast<uint4*>(hout + v * 8);
    op[0] = make_uint4(w[0], w[1], w[2], w[3]);
    op[1] = make_uint4(w[4], w[5], w[6], w[7]);
}

// ---------------- Generic fused layer, f16 in/out, 8-deep gather pipeline ----------------
// WPN = DIN/8 lanes per node; each lane loads one uint4 (8 f16) per edge.

template <int DIN, int DOUT>
__global__ __launch_bounds__(256) void sage_f16(const uint4* __restrict__ hin,
                                                const int* __restrict__ rp,
                                                const int* __restrict__ col,
                                                const float* __restrict__ W,
                                                const float* __restrict__ bias,
                                                unsigned int* __restrict__ hout, int n) {
    constexpr int WPN = DIN / 8;
    constexpr int NPB = 256 / WPN;
    constexpr int OPT = DOUT / WPN;
    __shared__ float sW[DIN * DOUT];
    __shared__ float sB[DOUT];
    __shared__ float sH[NPB][DIN + 1];

    int tid = threadIdx.x;
    for (int i = tid; i < DIN * DOUT; i += 256) sW[i] = W[i];
    if (tid < DOUT) sB[tid] = bias[tid];

    int sub = tid / WPN;
    int t = tid % WPN;
    int v = blockIdx.x * NPB + sub;

    if (v < n) {
        int r0 = rp[v], r1 = rp[v + 1];
        const __half2 z = __float2half2_rn(0.f);
        __half2 acc[4][4];
#pragma unroll
        for (int s = 0; s < 4; ++s)
#pragma unroll
            for (int q = 0; q < 4; ++q) acc[s][q] = z;
        int j = r0;
        // 8-deep: issue 8 independent row loads, then fold into 4 acc sets.
        for (; j + 8 <= r1; j += 8) {
            uint4 w[8];
#pragma unroll
            for (int k = 0; k < 8; ++k) w[k] = hin[col[j + k] * WPN + t];
#pragma unroll
            for (int k = 0; k < 8; ++k) {
                __half2* a = acc[k & 3];
                a[0] = __hadd2(a[0], u2h(w[k].x));
                a[1] = __hadd2(a[1], u2h(w[k].y));
                a[2] = __hadd2(a[2], u2h(w[k].z));
                a[3] = __hadd2(a[3], u2h(w[k].w));
            }
        }
        for (; j + 4 <= r1; j += 4) {
            uint4 w[4];
#pragma unroll
            for (int k = 0; k < 4; ++k) w[k] = hin[col[j + k] * WPN + t];
#pragma unroll
            for (int k = 0; k < 4; ++k) {
                __half2* a = acc[k];
                a[0] = __hadd2(a[0], u2h(w[k].x));
                a[1] = __hadd2(a[1], u2h(w[k].y));
                a[2] = __hadd2(a[2], u2h(w[k].z));
                a[3] = __hadd2(a[3], u2h(w[k].w));
            }
        }
        for (; j < r1; ++j) {
            uint4 w = hin[col[j] * WPN + t];
            acc[0][0] = __hadd2(acc[0][0], u2h(w.x));
            acc[0][1] = __hadd2(acc[0][1], u2h(w.y));
            acc[0][2] = __hadd2(acc[0][2], u2h(w.z));
            acc[0][3] = __hadd2(acc[0][3], u2h(w.w));
        }
#pragma unroll
        for (int q = 0; q < 4; ++q)
            acc[0][q] = __hadd2(__hadd2(acc[0][q], acc[1][q]),
                                __hadd2(acc[2][q], acc[3][q]));
        uint4 ws = hin[v * WPN + t];
        unsigned swd[4] = {ws.x, ws.y, ws.z, ws.w};
        float inv = 1.0f / (float)(r1 - r0 + 1);
#pragma unroll
        for (int q = 0; q < 4; ++q) {
            float2 f = __half22float2(acc[0][q]);
            float2 s = u2f2(swd[q]);
            sH[sub][t * 8 + 2 * q + 0] = (f.x + s.x) * inv;
            sH[sub][t * 8 + 2 * q + 1] = (f.y + s.y) * inv;
        }
    }
    __syncthreads();
    if (v < n) {
        int o0 = t * OPT;
        float accO[OPT];
#pragma unroll
        for (int i = 0; i < OPT; ++i) accO[i] = sB[o0 + i];
#pragma unroll 4
        for (int k = 0; k < DIN; ++k) {
            float hk = sH[sub][k];
#pragma unroll
            for (int i = 0; i < OPT; ++i) accO[i] += hk * sW[k * DOUT + o0 + i];
        }
        unsigned wds[OPT / 2];
#pragma unroll
        for (int i = 0; i < OPT; i += 2)
            wds[i / 2] = packh2(fmaxf(accO[i], 0.f), fmaxf(accO[i + 1], 0.f));
        unsigned* op = hout + v * (DOUT / 2) + o0 / 2;
        if constexpr (OPT / 2 == 4) {
            *reinterpret_cast<uint4*>(op) = make_uint4(wds[0], wds[1], wds[2], wds[3]);
        } else if constexpr (OPT / 2 == 8) {
            reinterpret_cast<uint4*>(op)[0] = make_uint4(wds[0], wds[1], wds[2], wds[3]);
            reinterpret_cast<uint4*>(op)[1] = make_uint4(wds[4], wds[5], wds[6], wds[7]);
        } else {
            *reinterpret_cast<uint2*>(op) = make_uint2(wds[0], wds[1]);
        }
    }
}

// ---------------- Pooling: per-graph mean, f16 input ----------------

__device__ __forceinline__ int lower_bound_i(const int* __restrict__ a, int n, int key) {
    int lo = 0, hi = n;
    while (lo < hi) {
        int m = (lo + hi) >> 1;
        if (a[m] < key) lo = m + 1; else hi = m;
    }
    return lo;
}

__global__ __launch_bounds__(256) void pool_f16(const unsigned int* __restrict__ h32,
                                                const int* __restrict__ gids,
                                                float* __restrict__ out, int n) {
    int bx = blockIdx.x;
    int g = bx >> 3, s = bx & 7;
    int start = lower_bound_i(gids, n, g);
    int end = lower_bound_i(gids, n, g + 1);
    int len = end - start;
    float inv = 1.0f / (float)(len > 0 ? len : 1);
    int chunk = (len + 7) / 8;
    int s0 = start + s * chunk;
    int s1 = min(s0 + chunk, end);
    int t = threadIdx.x;
    int d = t & 31, j = t >> 5;
    float a0 = 0.f, a1 = 0.f;
    for (int i = s0 + j; i < s1; i += 8) {
        float2 f = u2f2(h32[(size_t)i * 32 + d]);
        a0 += f.x;
        a1 += f.y;
    }
    __shared__ float red[8][32][2];
    red[j][d][0] = a0;
    red[j][d][1] = a1;
    __syncthreads();
    if (t < 64) {
        int dd = t & 31, e = t >> 5;
        float tot = 0.f;
#pragma unroll
        for (int k = 0; k < 8; ++k) tot += red[k][dd][e];
        atomicAdd(&out[g * 64 + 2 * dd + e], tot * inv);
    }
}

// ---------------- launch ----------------

extern "C" void kernel_launch(void* const* d_in, const int* in_sizes, int n_in,
                              void* d_out, int out_size, void* d_ws, size_t ws_size,
                              hipStream_t stream) {
    const int N = N_NODES, E = N_EDGES;
    const float* feat = (const float*)d_in[0];
    const int* src = (const int*)d_in[1];
    const int* dst = (const int*)d_in[2];
    const int* gids = (const int*)d_in[3];
    const float* W1 = (const float*)d_in[4];
    const float* b1 = (const float*)d_in[5];
    const float* W2 = (const float*)d_in[6];
    const float* b2 = (const float*)d_in[7];
    const float* W3 = (const float*)d_in[8];
    const float* b3 = (const float*)d_in[9];
    const float* W4 = (const float*)d_in[10];
    const float* b4 = (const float*)d_in[11];
    float* out = (float*)d_out;

    // workspace layout
    int* rp = (int*)d_ws;                       // N+1
    int* gcnt = rp + (N + 1);                   // 256
    int* cntmat = gcnt + 256;                   // NBLK_BIN*256
    int* col = cntmat + (size_t)NBLK_BIN * 256; // E
    size_t off = (size_t)((char*)(col + E) - (char*)d_ws);
    off = (off + 255) & ~(size_t)255;
    unsigned int* h1 = (unsigned int*)((char*)d_ws + off);   // f16 N*16 (N*8 words)
    unsigned int* h2 = h1 + (size_t)N * 8;                   // f16 N*32 (N*16 words)
    unsigned int* h3 = h2 + (size_t)N * 16;                  // f16 N*64 (N*32 words)
    unsigned int* h4 = h3 + (size_t)N * 32;                  // f16 N*64 (N*32 words)
    uint2* rec = (uint2*)h3;  // 12.8MB edge records; dead before layer-3 writes h3

    hipMemsetAsync(out, 0, (size_t)N_GRAPHS * 64 * sizeof(float), stream);

    bin_count<<<NBLK_BIN, 256, 0, stream>>>(dst, cntmat, E);
    bin_scan<<<NB_BKT, 256, 0, stream>>>(cntmat, gcnt, NBLK_BIN);
    bin_write<<<NBLK_BIN, 256, 0, stream>>>(dst, src, cntmat, gcnt, rec, E);
    fill_bucket<<<NB_BKT, 256, 0, stream>>>(rec, gcnt, rp, col, N);

    sage_layer1<<<(N + 255) / 256, 256, 0, stream>>>(feat, rp, col, W1, b1, h1, N);
    // layer2: DIN=16 WPN=2 NPB=128
    sage_f16<16, 32><<<(N + 127) / 128, 256, 0, stream>>>(
        (const uint4*)h1, rp, col, W2, b2, h2, N);
    // layer3: DIN=32 WPN=4 NPB=64
    sage_f16<32, 64><<<(N + 63) / 64, 256, 0, stream>>>(
        (const uint4*)h2, rp, col, W3, b3, h3, N);
    // layer4: DIN=64 WPN=8 NPB=32
    sage_f16<64, 64><<<(N + 31) / 32, 256, 0, stream>>>(
        (const uint4*)h3, rp, col, W4, b4, h4, N);

    pool_f16<<<N_GRAPHS * 8, 256, 0, stream>>>(h4, gids, out, N);
}